// Round 1
// baseline (2938.370 us; speedup 1.0000x reference)
//
#include <hip/hip_runtime.h>
#include <math.h>

// DualStreamBlock: B=4, DIM=96, DIM3=288, H=W=64, L=4096, DSTATE=16
// di=192, di3=576, r=6, r3=18
#define L 4096

struct GemmP {
  const float* A0; const float* A1; const float* W;
  const float* abias; const float* ebias; const float* res;
  float* out0; float* out1;
  int K, K1, N, lda, ldo, split;
};

__device__ __forceinline__ float softplus_f(float x) {
  return fmaxf(x, 0.f) + log1pf(__expf(-fabsf(x)));
}
__device__ __forceinline__ float silu_f(float x) {
  return x / (1.f + __expf(-x));
}

// AMODE: 0 = A row-major [M x lda]; 1 = A chan-major (B,K,L) (+optional row bias abias[b*K+k]);
//        2 = concat chan-major: k<K1 from A0 (K1 ch), else A1 (K-K1 ch)
// EPI:   0 = row-major store out0[m*ldo+n]
//        1 = split transpose store: n<split -> out0 chan-major, else out1 chan-major (both `split` channels)
//        2 = chan-major store (B,N,L)
//        3 = softplus(x + ebias[n]) chan-major
//        4 = silu(x + ebias[n]) chan-major
//        5 = (x + ebias[n]) chan-major
//        6 = res(chan-major) + x -> out0 chan-major
template<int AMODE, int EPI>
__global__ __launch_bounds__(256) void gemm_k(GemmP p) {
  __shared__ __align__(16) float As[16][64];
  __shared__ __align__(16) float Bs[16][64];
  const int tid = threadIdx.x;
  const int kidx = tid >> 4;
  const int li4 = (tid & 15) << 2;
  const int r0 = (tid & 15) << 2;   // rows (l) -- consecutive tid -> consecutive l
  const int c0 = (tid >> 4) << 2;   // cols (n)
  const int n0 = blockIdx.x * 64;
  const int m0 = blockIdx.y * 64;
  const int b = m0 >> 12;           // /4096
  const int l0 = m0 & (L - 1);
  float acc[4][4] = {};

  for (int k0 = 0; k0 < p.K; k0 += 16) {
    __syncthreads();
    if (AMODE == 0) {
      const int row = tid >> 2;
      const int kk4 = (tid & 3) << 2;
      const float* src = p.A0 + (size_t)(m0 + row) * p.lda;
      #pragma unroll
      for (int j = 0; j < 4; ++j) {
        int k = k0 + kk4 + j;
        As[kk4 + j][row] = (k < p.K) ? src[k] : 0.f;
      }
    } else {
      int k = k0 + kidx;
      float4 v = make_float4(0.f, 0.f, 0.f, 0.f);
      if (k < p.K) {
        const float* src;
        if (AMODE == 2 && k >= p.K1) {
          src = p.A1 + ((size_t)b * (p.K - p.K1) + (k - p.K1)) * L + l0 + li4;
        } else {
          int kch = (AMODE == 2) ? p.K1 : p.K;
          src = p.A0 + ((size_t)b * kch + k) * L + l0 + li4;
        }
        v = *(const float4*)src;
        if (AMODE == 1 && p.abias) {
          float bb = p.abias[b * p.K + k];
          v.x += bb; v.y += bb; v.z += bb; v.w += bb;
        }
      }
      *(float4*)&As[kidx][li4] = v;
    }
    {
      int k = k0 + kidx;
      #pragma unroll
      for (int j = 0; j < 4; ++j) {
        int n = n0 + li4 + j;
        Bs[kidx][li4 + j] = (k < p.K && n < p.N) ? p.W[(size_t)k * p.N + n] : 0.f;
      }
    }
    __syncthreads();
    #pragma unroll
    for (int kk = 0; kk < 16; ++kk) {
      float4 a = *(const float4*)&As[kk][r0];
      float4 bq = *(const float4*)&Bs[kk][c0];
      float av[4] = {a.x, a.y, a.z, a.w};
      float bv[4] = {bq.x, bq.y, bq.z, bq.w};
      #pragma unroll
      for (int i = 0; i < 4; ++i)
        #pragma unroll
        for (int j = 0; j < 4; ++j)
          acc[i][j] = fmaf(av[i], bv[j], acc[i][j]);
    }
  }

  if (EPI == 0) {
    #pragma unroll
    for (int i = 0; i < 4; ++i) {
      int m = m0 + r0 + i;
      #pragma unroll
      for (int j = 0; j < 4; ++j) {
        int n = n0 + c0 + j;
        if (n < p.N) p.out0[(size_t)m * p.ldo + n] = acc[i][j];
      }
    }
  } else {
    #pragma unroll
    for (int j = 0; j < 4; ++j) {
      int n = n0 + c0 + j;
      if (n >= p.N) continue;
      float v0 = acc[0][j], v1 = acc[1][j], v2 = acc[2][j], v3 = acc[3][j];
      if (EPI == 3) {
        float eb = p.ebias[n];
        v0 = softplus_f(v0 + eb); v1 = softplus_f(v1 + eb);
        v2 = softplus_f(v2 + eb); v3 = softplus_f(v3 + eb);
      }
      if (EPI == 4) {
        float eb = p.ebias[n];
        v0 = silu_f(v0 + eb); v1 = silu_f(v1 + eb);
        v2 = silu_f(v2 + eb); v3 = silu_f(v3 + eb);
      }
      if (EPI == 5) {
        float eb = p.ebias[n];
        v0 += eb; v1 += eb; v2 += eb; v3 += eb;
      }
      float* dst;
      if (EPI == 1) {
        dst = (n < p.split) ? p.out0 + ((size_t)b * p.split + n) * L + l0 + r0
                            : p.out1 + ((size_t)b * p.split + (n - p.split)) * L + l0 + r0;
      } else {
        dst = p.out0 + ((size_t)b * p.N + n) * L + l0 + r0;
      }
      float4 vv = make_float4(v0, v1, v2, v3);
      if (EPI == 6) {
        const float4 rr = *(const float4*)(p.res + ((size_t)b * p.N + n) * L + l0 + r0);
        vv.x += rr.x; vv.y += rr.y; vv.z += rr.z; vv.w += rr.w;
      }
      *(float4*)dst = vv;
    }
  }
}

// causal depthwise conv k=4 (left pad 3) + bias + silu; x,y: (B, Dch, L) chan-major
__global__ __launch_bounds__(256) void dwconv_silu_k(const float* __restrict__ x,
    const float* __restrict__ w, const float* __restrict__ bias,
    float* __restrict__ y, int total, int Dch) {
  int idx = blockIdx.x * 256 + threadIdx.x;
  if (idx >= total) return;
  int l = idx & (L - 1);
  int bd = idx >> 12;
  int d = bd % Dch;
  const float* xs = x + (size_t)bd * L;
  const float w0 = w[d * 4 + 0], w1 = w[d * 4 + 1], w2 = w[d * 4 + 2], w3 = w[d * 4 + 3];
  float s = bias[d];
  s = fmaf(w3, xs[l], s);
  if (l >= 1) s = fmaf(w2, xs[l - 1], s);
  if (l >= 2) s = fmaf(w1, xs[l - 2], s);
  if (l >= 3) s = fmaf(w0, xs[l - 3], s);
  y[idx] = silu_f(s);
}

// LayerNorm over channel dim C per (b,l); x,out: (B,C,L) chan-major
__global__ __launch_bounds__(256) void ln_k(const float* __restrict__ x,
    const float* __restrict__ g, const float* __restrict__ bb,
    float* __restrict__ out, int C) {
  int l = blockIdx.x * 256 + threadIdx.x;
  int b = blockIdx.y;
  const float* xb = x + (size_t)b * C * L + l;
  float s = 0.f, sq = 0.f;
  for (int c = 0; c < C; ++c) {
    float v = xb[(size_t)c * L];
    s += v; sq = fmaf(v, v, sq);
  }
  float m = s / C;
  float var = sq / C - m * m;
  float rs = rsqrtf(var + 1e-5f);
  float* ob = out + (size_t)b * C * L + l;
  for (int c = 0; c < C; ++c) {
    float v = xb[(size_t)c * L];
    ob[(size_t)c * L] = (v - m) * rs * g[c] + bb[c];
  }
}

// Selective scan. One channel (b,d) per 16 lanes (lane = state n).
// u,dlt,zb,y: (B,Dch,L) chan-major (dlt already softplus'ed+biased).
// xdbl: (B,L,ldx) row-major; Bs at col roff+n, Cs at col roff+16+n.
__global__ __launch_bounds__(256) void scan_k(const float* __restrict__ u,
    const float* __restrict__ dlt, const float* __restrict__ Alog,
    const float* __restrict__ xdbl, int ldx, int roff,
    const float* __restrict__ Dp, const float* __restrict__ zb,
    float* __restrict__ y, int Dch) {
  const int tid = threadIdx.x;
  const int lane = tid & 15;
  const int chid = blockIdx.x * 16 + (tid >> 4);
  const int b = chid / Dch;
  const int d = chid - b * Dch;
  const float An = -__expf(Alog[d * 16 + lane]);
  const float Dd = Dp[d];
  const size_t base = (size_t)chid * L;
  const float* up = u + base;
  const float* dp = dlt + base;
  const float* zp = zb + base;
  float* yp = y + base;
  const float* xrow = xdbl + (size_t)b * L * ldx + roff + lane;
  float h = 0.f;
  float d0[8], u0[8], B0[8], C0[8], z0[8];
  float d1[8], u1[8], B1[8], C1[8], z1[8];

#define SLOAD(t0, dd, uu, BB, CC, zz) { \
  _Pragma("unroll") \
  for (int i = 0; i < 8; ++i) { \
    int t = (t0) + i; \
    dd[i] = dp[t]; uu[i] = up[t]; zz[i] = zp[t]; \
    const float* rr = xrow + (size_t)t * ldx; \
    BB[i] = rr[0]; CC[i] = rr[16]; \
  } }
#define SCOMP(t0, dd, uu, BB, CC, zz) { \
  _Pragma("unroll") \
  for (int i = 0; i < 8; ++i) { \
    float dl = dd[i]; \
    float e = __expf(dl * An); \
    h = fmaf(e, h, dl * uu[i] * BB[i]); \
    float pv = h * CC[i]; \
    pv += __shfl_xor(pv, 1, 16); \
    pv += __shfl_xor(pv, 2, 16); \
    pv += __shfl_xor(pv, 4, 16); \
    pv += __shfl_xor(pv, 8, 16); \
    if (lane == 0) { \
      float zv = zz[i]; \
      yp[(t0) + i] = (pv + Dd * uu[i]) * (zv / (1.f + __expf(-zv))); \
    } \
  } }

  SLOAD(0, d0, u0, B0, C0, z0);
  for (int t0 = 0; t0 < L; t0 += 16) {
    SLOAD(t0 + 8, d1, u1, B1, C1, z1);
    SCOMP(t0, d0, u0, B0, C0, z0);
    if (t0 + 16 < L) SLOAD(t0 + 16, d0, u0, B0, C0, z0);
    SCOMP(t0 + 8, d1, u1, B1, C1, z1);
  }
#undef SLOAD
#undef SCOMP
}

extern "C" void kernel_launch(void* const* d_in, const int* in_sizes, int n_in,
                              void* d_out, int out_size, void* d_ws, size_t ws_size,
                              hipStream_t stream) {
  const float* m_ll    = (const float*)d_in[0];
  const float* m_high  = (const float*)d_in[1];
  const float* zanc    = (const float*)d_in[2];
  const float* Kin     = (const float*)d_in[3];
  const float* Qin     = (const float*)d_in[4];
  const float* s_in_w  = (const float*)d_in[5];
  const float* s_conv_w= (const float*)d_in[6];
  const float* s_conv_b= (const float*)d_in[7];
  const float* s_x_w   = (const float*)d_in[8];
  const float* s_dt_w  = (const float*)d_in[9];
  const float* s_dt_b  = (const float*)d_in[10];
  const float* s_Alog  = (const float*)d_in[11];
  const float* s_D     = (const float*)d_in[12];
  const float* s_out_w = (const float*)d_in[13];
  const float* t_in_w  = (const float*)d_in[14];
  const float* t_conv_w= (const float*)d_in[15];
  const float* t_conv_b= (const float*)d_in[16];
  const float* t_kln_g = (const float*)d_in[17];
  const float* t_kln_b = (const float*)d_in[18];
  const float* t_k_w   = (const float*)d_in[19];
  const float* t_k_b   = (const float*)d_in[20];
  const float* t_qln_g = (const float*)d_in[21];
  const float* t_qln_b = (const float*)d_in[22];
  const float* t_q_w   = (const float*)d_in[23];
  const float* t_q_b   = (const float*)d_in[24];
  const float* t_dtbc_w= (const float*)d_in[25];
  const float* t_dt_w  = (const float*)d_in[26];
  const float* t_dt_b  = (const float*)d_in[27];
  const float* t_gate_w= (const float*)d_in[28];
  const float* t_gate_b= (const float*)d_in[29];
  const float* t_Alog  = (const float*)d_in[30];
  const float* t_D     = (const float*)d_in[31];
  const float* t_out_w = (const float*)d_in[32];

  float* out1 = (float*)d_out;               // (4, 96, 4096)
  float* out2 = out1 + (size_t)4 * 96 * L;   // (4, 288, 4096)
  float* ws = (float*)d_ws;
  dim3 blk(256);

  // ---------------- SSS stream (runs first; uses low workspace region) ----
  float* xin  = ws;                 // (4,192,L)  -> later delta
  float* zg   = ws + 3145728;       // (4,192,L)
  float* xc   = ws + 6291456;       // (4,192,L)
  float* xdbl = ws + 9437184;       // (16384,38)
  float* yb   = ws + 10059776;      // (4,192,L)

  { GemmP p{}; p.A0 = m_ll; p.K = 96; p.abias = zanc; p.W = s_in_w; p.N = 384;
    p.out0 = xin; p.out1 = zg; p.split = 192;
    gemm_k<1, 1><<<dim3(6, 256), blk, 0, stream>>>(p); }
  dwconv_silu_k<<<dim3(3145728 / 256), blk, 0, stream>>>(xin, s_conv_w, s_conv_b, xc, 3145728, 192);
  { GemmP p{}; p.A0 = xc; p.K = 192; p.W = s_x_w; p.N = 38; p.out0 = xdbl; p.ldo = 38;
    gemm_k<1, 0><<<dim3(1, 256), blk, 0, stream>>>(p); }
  { GemmP p{}; p.A0 = xdbl; p.lda = 38; p.K = 6; p.W = s_dt_w; p.N = 192; p.ebias = s_dt_b; p.out0 = xin;
    gemm_k<0, 3><<<dim3(3, 256), blk, 0, stream>>>(p); }
  scan_k<<<dim3(48), blk, 0, stream>>>(xc, xin, s_Alog, xdbl, 38, 6, s_D, zg, yb, 192);
  { GemmP p{}; p.A0 = yb; p.K = 192; p.W = s_out_w; p.N = 96; p.res = m_ll; p.out0 = out1;
    gemm_k<1, 6><<<dim3(2, 256), blk, 0, stream>>>(p); }

  // ---------------- STS stream (reuses workspace; needs ~154 MB total) ----
  float* xin3  = ws;                // (4,576,L) -> Kn -> Qn -> delta3
  float* xc3   = ws + 9437184;      // (4,576,L)
  float* kp    = ws + 18874368;     // Kp -> zg3
  float* qp    = ws + 28311552;     // Qp -> y3
  float* xdbl3 = ws + 37748736;     // (16384,50)

  { GemmP p{}; p.A0 = m_high; p.K = 288; p.W = t_in_w; p.N = 576; p.out0 = xin3;
    gemm_k<1, 2><<<dim3(9, 256), blk, 0, stream>>>(p); }
  dwconv_silu_k<<<dim3(9437184 / 256), blk, 0, stream>>>(xin3, t_conv_w, t_conv_b, xc3, 9437184, 576);
  ln_k<<<dim3(16, 4), blk, 0, stream>>>(Kin, t_kln_g, t_kln_b, xin3, 288);
  { GemmP p{}; p.A0 = xin3; p.K = 288; p.W = t_k_w; p.N = 576; p.ebias = t_k_b; p.out0 = kp;
    gemm_k<1, 4><<<dim3(9, 256), blk, 0, stream>>>(p); }
  ln_k<<<dim3(16, 4), blk, 0, stream>>>(Qin, t_qln_g, t_qln_b, xin3, 288);
  { GemmP p{}; p.A0 = xin3; p.K = 288; p.W = t_q_w; p.N = 576; p.ebias = t_q_b; p.out0 = qp;
    gemm_k<1, 4><<<dim3(9, 256), blk, 0, stream>>>(p); }
  { GemmP p{}; p.A0 = xc3; p.A1 = kp; p.K = 1152; p.K1 = 576; p.W = t_dtbc_w; p.N = 50;
    p.out0 = xdbl3; p.ldo = 50;
    gemm_k<2, 0><<<dim3(1, 256), blk, 0, stream>>>(p); }
  { GemmP p{}; p.A0 = xdbl3; p.lda = 50; p.K = 18; p.W = t_dt_w; p.N = 576; p.ebias = t_dt_b; p.out0 = xin3;
    gemm_k<0, 3><<<dim3(9, 256), blk, 0, stream>>>(p); }
  { GemmP p{}; p.A0 = xc3; p.A1 = qp; p.K = 1152; p.K1 = 576; p.W = t_gate_w; p.N = 576;
    p.ebias = t_gate_b; p.out0 = kp;
    gemm_k<2, 5><<<dim3(9, 256), blk, 0, stream>>>(p); }
  scan_k<<<dim3(144), blk, 0, stream>>>(xc3, xin3, t_Alog, xdbl3, 50, 18, t_D, kp, qp, 576);
  { GemmP p{}; p.A0 = qp; p.K = 576; p.W = t_out_w; p.N = 288; p.res = m_high; p.out0 = out2;
    gemm_k<1, 6><<<dim3(5, 256), blk, 0, stream>>>(p); }
}

// Round 2
// 1791.628 us; speedup vs baseline: 1.6401x; 1.6401x over previous
//
#include <hip/hip_runtime.h>
#include <math.h>

// DualStreamBlock: B=4, DIM=96, DIM3=288, H=W=64, L=4096, DSTATE=16
// di=192, di3=576, r=6, r3=18
#define L 4096

struct GemmP {
  const float* A0; const float* A1; const float* W;
  const float* abias; const float* ebias; const float* res;
  float* out0; float* out1;
  int K, K1, N, lda, ldo, split;
};

__device__ __forceinline__ float softplus_f(float x) {
  return fmaxf(x, 0.f) + log1pf(__expf(-fabsf(x)));
}
__device__ __forceinline__ float silu_f(float x) {
  return x / (1.f + __expf(-x));
}

// AMODE: 0 = A row-major [M x lda]; 1 = A chan-major (B,K,L) (+optional row bias abias[b*K+k]);
//        2 = concat chan-major: k<K1 from A0 (K1 ch), else A1 (K-K1 ch)
// EPI:   0 = row-major store out0[m*ldo+n]
//        2 = chan-major store (B,N,L)
//        3 = softplus(x + ebias[n]) chan-major
//        4 = silu(x + ebias[n]) chan-major
//        6 = res(chan-major) + x -> out0 chan-major
//        7 = row-major + ebias: out0[m*ldo+n]
//        8 = split: n<split -> out0 chan-major; n>=split -> out1 row-major (ld=split)
template<int AMODE, int EPI>
__global__ __launch_bounds__(256) void gemm_k(GemmP p) {
  __shared__ __align__(16) float As[16][64];
  __shared__ __align__(16) float Bs[16][64];
  const int tid = threadIdx.x;
  const int kidx = tid >> 4;
  const int li4 = (tid & 15) << 2;
  const int r0 = (tid & 15) << 2;   // rows (l) -- consecutive tid -> consecutive l
  const int c0 = (tid >> 4) << 2;   // cols (n)
  const int n0 = blockIdx.x * 64;
  const int m0 = blockIdx.y * 64;
  const int b = m0 >> 12;           // /4096
  const int l0 = m0 & (L - 1);
  float acc[4][4] = {};

  for (int k0 = 0; k0 < p.K; k0 += 16) {
    __syncthreads();
    if (AMODE == 0) {
      const int row = tid >> 2;
      const int kk4 = (tid & 3) << 2;
      const float* src = p.A0 + (size_t)(m0 + row) * p.lda;
      #pragma unroll
      for (int j = 0; j < 4; ++j) {
        int k = k0 + kk4 + j;
        As[kk4 + j][row] = (k < p.K) ? src[k] : 0.f;
      }
    } else {
      int k = k0 + kidx;
      float4 v = make_float4(0.f, 0.f, 0.f, 0.f);
      if (k < p.K) {
        const float* src;
        if (AMODE == 2 && k >= p.K1) {
          src = p.A1 + ((size_t)b * (p.K - p.K1) + (k - p.K1)) * L + l0 + li4;
        } else {
          int kch = (AMODE == 2) ? p.K1 : p.K;
          src = p.A0 + ((size_t)b * kch + k) * L + l0 + li4;
        }
        v = *(const float4*)src;
        if (AMODE == 1 && p.abias) {
          float bb = p.abias[b * p.K + k];
          v.x += bb; v.y += bb; v.z += bb; v.w += bb;
        }
      }
      *(float4*)&As[kidx][li4] = v;
    }
    {
      int k = k0 + kidx;
      #pragma unroll
      for (int j = 0; j < 4; ++j) {
        int n = n0 + li4 + j;
        Bs[kidx][li4 + j] = (k < p.K && n < p.N) ? p.W[(size_t)k * p.N + n] : 0.f;
      }
    }
    __syncthreads();
    #pragma unroll
    for (int kk = 0; kk < 16; ++kk) {
      float4 a = *(const float4*)&As[kk][r0];
      float4 bq = *(const float4*)&Bs[kk][c0];
      float av[4] = {a.x, a.y, a.z, a.w};
      float bv[4] = {bq.x, bq.y, bq.z, bq.w};
      #pragma unroll
      for (int i = 0; i < 4; ++i)
        #pragma unroll
        for (int j = 0; j < 4; ++j)
          acc[i][j] = fmaf(av[i], bv[j], acc[i][j]);
    }
  }

  if (EPI == 0) {
    #pragma unroll
    for (int i = 0; i < 4; ++i) {
      int m = m0 + r0 + i;
      #pragma unroll
      for (int j = 0; j < 4; ++j) {
        int n = n0 + c0 + j;
        if (n < p.N) p.out0[(size_t)m * p.ldo + n] = acc[i][j];
      }
    }
  } else if (EPI == 7) {
    if (n0 + c0 < p.N) {
      #pragma unroll
      for (int i = 0; i < 4; ++i) {
        float4 v;
        v.x = acc[i][0] + p.ebias[n0 + c0 + 0];
        v.y = acc[i][1] + p.ebias[n0 + c0 + 1];
        v.z = acc[i][2] + p.ebias[n0 + c0 + 2];
        v.w = acc[i][3] + p.ebias[n0 + c0 + 3];
        *(float4*)&p.out0[(size_t)(m0 + r0 + i) * p.ldo + n0 + c0] = v;
      }
    }
  } else if (EPI == 8) {
    if (n0 + c0 < p.split) {
      #pragma unroll
      for (int j = 0; j < 4; ++j) {
        int n = n0 + c0 + j;
        float4 vv = make_float4(acc[0][j], acc[1][j], acc[2][j], acc[3][j]);
        *(float4*)&p.out0[((size_t)b * p.split + n) * L + l0 + r0] = vv;
      }
    } else {
      #pragma unroll
      for (int i = 0; i < 4; ++i) {
        float4 v = make_float4(acc[i][0], acc[i][1], acc[i][2], acc[i][3]);
        *(float4*)&p.out1[(size_t)(m0 + r0 + i) * p.split + (n0 + c0 - p.split)] = v;
      }
    }
  } else {
    #pragma unroll
    for (int j = 0; j < 4; ++j) {
      int n = n0 + c0 + j;
      if (n >= p.N) continue;
      float v0 = acc[0][j], v1 = acc[1][j], v2 = acc[2][j], v3 = acc[3][j];
      if (EPI == 3) {
        float eb = p.ebias[n];
        v0 = softplus_f(v0 + eb); v1 = softplus_f(v1 + eb);
        v2 = softplus_f(v2 + eb); v3 = softplus_f(v3 + eb);
      }
      if (EPI == 4) {
        float eb = p.ebias[n];
        v0 = silu_f(v0 + eb); v1 = silu_f(v1 + eb);
        v2 = silu_f(v2 + eb); v3 = silu_f(v3 + eb);
      }
      float* dst = p.out0 + ((size_t)b * p.N + n) * L + l0 + r0;
      float4 vv = make_float4(v0, v1, v2, v3);
      if (EPI == 6) {
        const float4 rr = *(const float4*)(p.res + ((size_t)b * p.N + n) * L + l0 + r0);
        vv.x += rr.x; vv.y += rr.y; vv.z += rr.z; vv.w += rr.w;
      }
      *(float4*)dst = vv;
    }
  }
}

// causal depthwise conv k=4 (left pad 3) + bias + silu; x,y: (B, Dch, L) chan-major
__global__ __launch_bounds__(256) void dwconv_silu_k(const float* __restrict__ x,
    const float* __restrict__ w, const float* __restrict__ bias,
    float* __restrict__ y, int total, int Dch) {
  int idx = blockIdx.x * 256 + threadIdx.x;
  if (idx >= total) return;
  int l = idx & (L - 1);
  int bd = idx >> 12;
  int d = bd % Dch;
  const float* xs = x + (size_t)bd * L;
  const float w0 = w[d * 4 + 0], w1 = w[d * 4 + 1], w2 = w[d * 4 + 2], w3 = w[d * 4 + 3];
  float s = bias[d];
  s = fmaf(w3, xs[l], s);
  if (l >= 1) s = fmaf(w2, xs[l - 1], s);
  if (l >= 2) s = fmaf(w1, xs[l - 2], s);
  if (l >= 3) s = fmaf(w0, xs[l - 3], s);
  y[idx] = silu_f(s);
}

// LayerNorm over channel dim C per (b,l); x,out: (B,C,L) chan-major
__global__ __launch_bounds__(256) void ln_k(const float* __restrict__ x,
    const float* __restrict__ g, const float* __restrict__ bb,
    float* __restrict__ out, int C) {
  int l = blockIdx.x * 256 + threadIdx.x;
  int b = blockIdx.y;
  const float* xb = x + (size_t)b * C * L + l;
  float s = 0.f, sq = 0.f;
  for (int c = 0; c < C; ++c) {
    float v = xb[(size_t)c * L];
    s += v; sq = fmaf(v, v, sq);
  }
  float m = s / C;
  float var = sq / C - m * m;
  float rs = rsqrtf(var + 1e-5f);
  float* ob = out + (size_t)b * C * L + l;
  for (int c = 0; c < C; ++c) {
    float v = xb[(size_t)c * L];
    ob[(size_t)c * L] = (v - m) * rs * g[c] + bb[c];
  }
}

// Chunked selective scan.
// Thread = (b, chunk c, channel d); lane dim = d (coalesced on row-major z/y).
// u, dlt: (B,Dch,L) chan-major. zT, yT: (B*L, Dch) row-major.
// xdbl: (B*L, ldx) rows; B at cols [roff, roff+16), C at [roff+16, roff+32).
// PF: (B*Dch, NC, 32): [0..16) = decay product P, [16..32) = F (pass1) then Hin (pass2).
// PASS 1: compute P, F (h_in = 0). PASS 3: h_in = Hin, emit y.
template<int PASS>
__global__ __launch_bounds__(64) void scan_chunk_k(
    const float* __restrict__ u, const float* __restrict__ dlt,
    const float* __restrict__ Alog,
    const float* __restrict__ xdbl, int ldx, int roff,
    const float* __restrict__ Dp, const float* __restrict__ zT,
    float* __restrict__ PF, float* __restrict__ yT,
    int Dch, int CLen)
{
  const int d = blockIdx.x * 64 + threadIdx.x;
  const int c = blockIdx.y;
  const int NCc = gridDim.y;
  const int b = blockIdx.z;
  const int ch = b * Dch + d;
  const int t0 = c * CLen;

  float An[16], h[16], P[16];
  #pragma unroll
  for (int n = 0; n < 16; ++n) {
    An[n] = -__expf(Alog[d * 16 + n]);
    P[n] = 1.f;
    h[n] = 0.f;
  }
  if (PASS == 3) {
    const float4* hp = (const float4*)(PF + ((size_t)ch * NCc + c) * 32 + 16);
    #pragma unroll
    for (int q = 0; q < 4; ++q) {
      float4 hv = hp[q];
      h[4 * q] = hv.x; h[4 * q + 1] = hv.y; h[4 * q + 2] = hv.z; h[4 * q + 3] = hv.w;
    }
  }
  const float Dd = Dp[d];
  const float* up = u + (size_t)ch * L + t0;
  const float* dp = dlt + (size_t)ch * L + t0;
  const float* xr = xdbl + ((size_t)b * L + t0) * ldx + roff;
  const float* zr = zT + ((size_t)b * L + t0) * Dch + d;
  float* yr = yT + ((size_t)b * L + t0) * Dch + d;

  for (int t = 0; t < CLen; ++t) {
    float dl = dp[t];
    float uu = up[t];
    float w = dl * uu;
    const float2* bp = (const float2*)(xr + (size_t)t * ldx);
    float y = 0.f;
    #pragma unroll
    for (int q = 0; q < 8; ++q) {
      float2 bv = bp[q];
      float a0 = __expf(dl * An[2 * q]);
      float a1 = __expf(dl * An[2 * q + 1]);
      h[2 * q]     = fmaf(a0, h[2 * q],     w * bv.x);
      h[2 * q + 1] = fmaf(a1, h[2 * q + 1], w * bv.y);
      if (PASS == 1) {
        P[2 * q] *= a0;
        P[2 * q + 1] *= a1;
      } else {
        float2 cv = bp[q + 8];
        y = fmaf(h[2 * q], cv.x, y);
        y = fmaf(h[2 * q + 1], cv.y, y);
      }
    }
    if (PASS == 3) {
      float zv = zr[(size_t)t * Dch];
      y = fmaf(Dd, uu, y);
      yr[(size_t)t * Dch] = y * silu_f(zv);
    }
  }
  if (PASS == 1) {
    float* o = PF + ((size_t)ch * NCc + c) * 32;
    #pragma unroll
    for (int q = 0; q < 4; ++q) {
      ((float4*)o)[q] = make_float4(P[4 * q], P[4 * q + 1], P[4 * q + 2], P[4 * q + 3]);
      ((float4*)o)[q + 4] = make_float4(h[4 * q], h[4 * q + 1], h[4 * q + 2], h[4 * q + 3]);
    }
  }
}

// Stitch: per (channel, state), sequential over chunks.
// Rewrites F slot with Hin (incoming state for that chunk).
__global__ __launch_bounds__(256) void scan_mid_k(float* __restrict__ PF, int NCc, int total) {
  int idx = blockIdx.x * 256 + threadIdx.x;
  if (idx >= total) return;
  int ch = idx >> 4, n = idx & 15;
  float* base = PF + (size_t)ch * NCc * 32 + n;
  float hin = 0.f;
  for (int c = 0; c < NCc; ++c) {
    float Pv = base[(size_t)c * 32];
    float Fv = base[(size_t)c * 32 + 16];
    base[(size_t)c * 32 + 16] = hin;
    hin = fmaf(Pv, hin, Fv);
  }
}

extern "C" void kernel_launch(void* const* d_in, const int* in_sizes, int n_in,
                              void* d_out, int out_size, void* d_ws, size_t ws_size,
                              hipStream_t stream) {
  const float* m_ll    = (const float*)d_in[0];
  const float* m_high  = (const float*)d_in[1];
  const float* zanc    = (const float*)d_in[2];
  const float* Kin     = (const float*)d_in[3];
  const float* Qin     = (const float*)d_in[4];
  const float* s_in_w  = (const float*)d_in[5];
  const float* s_conv_w= (const float*)d_in[6];
  const float* s_conv_b= (const float*)d_in[7];
  const float* s_x_w   = (const float*)d_in[8];
  const float* s_dt_w  = (const float*)d_in[9];
  const float* s_dt_b  = (const float*)d_in[10];
  const float* s_Alog  = (const float*)d_in[11];
  const float* s_D     = (const float*)d_in[12];
  const float* s_out_w = (const float*)d_in[13];
  const float* t_in_w  = (const float*)d_in[14];
  const float* t_conv_w= (const float*)d_in[15];
  const float* t_conv_b= (const float*)d_in[16];
  const float* t_kln_g = (const float*)d_in[17];
  const float* t_kln_b = (const float*)d_in[18];
  const float* t_k_w   = (const float*)d_in[19];
  const float* t_k_b   = (const float*)d_in[20];
  const float* t_qln_g = (const float*)d_in[21];
  const float* t_qln_b = (const float*)d_in[22];
  const float* t_q_w   = (const float*)d_in[23];
  const float* t_q_b   = (const float*)d_in[24];
  const float* t_dtbc_w= (const float*)d_in[25];
  const float* t_dt_w  = (const float*)d_in[26];
  const float* t_dt_b  = (const float*)d_in[27];
  const float* t_gate_w= (const float*)d_in[28];
  const float* t_gate_b= (const float*)d_in[29];
  const float* t_Alog  = (const float*)d_in[30];
  const float* t_D     = (const float*)d_in[31];
  const float* t_out_w = (const float*)d_in[32];

  float* out1 = (float*)d_out;               // (4, 96, 4096)  = 1,572,864 floats
  float* out2 = out1 + (size_t)4 * 96 * L;   // (4, 288, 4096) = 4,718,592 floats
  float* ws = (float*)d_ws;
  dim3 blk(256);
  dim3 blk64(64);

  // ---------------- SSS stream ----------------
  float* xin  = ws;                 // (4,192,L) chan-major x_in -> later delta
  float* zT   = ws + 3145728;       // (16384,192) row-major z
  float* xc   = ws + 6291456;       // (4,192,L) chan-major u
  float* xdbl = ws + 9437184;       // (16384,38)
  float* yT   = ws + 10059776;      // (16384,192) row-major y
  float* PFs  = ws + 13205504;      // 768*128*32 = 3,145,728

  { GemmP p{}; p.A0 = m_ll; p.K = 96; p.abias = zanc; p.W = s_in_w; p.N = 384;
    p.out0 = xin; p.out1 = zT; p.split = 192;
    gemm_k<1, 8><<<dim3(6, 256), blk, 0, stream>>>(p); }
  dwconv_silu_k<<<dim3(3145728 / 256), blk, 0, stream>>>(xin, s_conv_w, s_conv_b, xc, 3145728, 192);
  { GemmP p{}; p.A0 = xc; p.K = 192; p.W = s_x_w; p.N = 38; p.out0 = xdbl; p.ldo = 38;
    gemm_k<1, 0><<<dim3(1, 256), blk, 0, stream>>>(p); }
  { GemmP p{}; p.A0 = xdbl; p.lda = 38; p.K = 6; p.W = s_dt_w; p.N = 192; p.ebias = s_dt_b; p.out0 = xin;
    gemm_k<0, 3><<<dim3(3, 256), blk, 0, stream>>>(p); }
  scan_chunk_k<1><<<dim3(3, 128, 4), blk64, 0, stream>>>(xc, xin, s_Alog, xdbl, 38, 6, s_D, zT, PFs, yT, 192, 32);
  scan_mid_k<<<dim3(48), blk, 0, stream>>>(PFs, 128, 12288);
  scan_chunk_k<3><<<dim3(3, 128, 4), blk64, 0, stream>>>(xc, xin, s_Alog, xdbl, 38, 6, s_D, zT, PFs, yT, 192, 32);
  { GemmP p{}; p.A0 = yT; p.lda = 192; p.K = 192; p.W = s_out_w; p.N = 96; p.res = m_ll; p.out0 = out1;
    gemm_k<0, 6><<<dim3(2, 256), blk, 0, stream>>>(p); }

  // ---------------- STS stream (reuses workspace) ----------------
  float* xin3  = ws;                // (4,576,L) x_in3 -> Kn -> Qn -> delta3
  float* xc3   = ws + 9437184;      // (4,576,L) chan-major u
  float* kp    = ws + 18874368;     // K_p (chan-major) -> z gate (row-major 16384x576)
  float* qp    = ws + 28311552;     // Q_p (chan-major) -> yT3 (row-major 16384x576)
  float* xdbl3 = ws + 37748736;     // (16384,50)
  float* PFt   = out2;              // 2304*64*32 = 4,718,592 == |out2| (dead until final GEMM)

  { GemmP p{}; p.A0 = m_high; p.K = 288; p.W = t_in_w; p.N = 576; p.out0 = xin3;
    gemm_k<1, 2><<<dim3(9, 256), blk, 0, stream>>>(p); }
  dwconv_silu_k<<<dim3(9437184 / 256), blk, 0, stream>>>(xin3, t_conv_w, t_conv_b, xc3, 9437184, 576);
  ln_k<<<dim3(16, 4), blk, 0, stream>>>(Kin, t_kln_g, t_kln_b, xin3, 288);
  { GemmP p{}; p.A0 = xin3; p.K = 288; p.W = t_k_w; p.N = 576; p.ebias = t_k_b; p.out0 = kp;
    gemm_k<1, 4><<<dim3(9, 256), blk, 0, stream>>>(p); }
  ln_k<<<dim3(16, 4), blk, 0, stream>>>(Qin, t_qln_g, t_qln_b, xin3, 288);
  { GemmP p{}; p.A0 = xin3; p.K = 288; p.W = t_q_w; p.N = 576; p.ebias = t_q_b; p.out0 = qp;
    gemm_k<1, 4><<<dim3(9, 256), blk, 0, stream>>>(p); }
  { GemmP p{}; p.A0 = xc3; p.A1 = kp; p.K = 1152; p.K1 = 576; p.W = t_dtbc_w; p.N = 50;
    p.out0 = xdbl3; p.ldo = 50;
    gemm_k<2, 0><<<dim3(1, 256), blk, 0, stream>>>(p); }
  { GemmP p{}; p.A0 = xdbl3; p.lda = 50; p.K = 18; p.W = t_dt_w; p.N = 576; p.ebias = t_dt_b; p.out0 = xin3;
    gemm_k<0, 3><<<dim3(9, 256), blk, 0, stream>>>(p); }
  { GemmP p{}; p.A0 = xc3; p.A1 = qp; p.K = 1152; p.K1 = 576; p.W = t_gate_w; p.N = 576;
    p.ebias = t_gate_b; p.out0 = kp; p.ldo = 576;
    gemm_k<2, 7><<<dim3(9, 256), blk, 0, stream>>>(p); }
  scan_chunk_k<1><<<dim3(9, 64, 4), blk64, 0, stream>>>(xc3, xin3, t_Alog, xdbl3, 50, 18, t_D, kp, PFt, qp, 576, 64);
  scan_mid_k<<<dim3(144), blk, 0, stream>>>(PFt, 64, 36864);
  scan_chunk_k<3><<<dim3(9, 64, 4), blk64, 0, stream>>>(xc3, xin3, t_Alog, xdbl3, 50, 18, t_D, kp, PFt, qp, 576, 64);
  { GemmP p{}; p.A0 = qp; p.lda = 576; p.K = 576; p.W = t_out_w; p.N = 288; p.res = m_high; p.out0 = out2;
    gemm_k<0, 6><<<dim3(5, 256), blk, 0, stream>>>(p); }
}

// Round 3
// 829.925 us; speedup vs baseline: 3.5405x; 2.1588x over previous
//
#include <hip/hip_runtime.h>
#include <math.h>

// DualStreamBlock: B=4, DIM=96, DIM3=288, H=W=64, L=4096, DSTATE=16
// di=192, di3=576, r=6, r3=18
#define L 4096

typedef unsigned short u16;
typedef float f32x4 __attribute__((ext_vector_type(4)));
typedef short s16x8 __attribute__((ext_vector_type(8)));
typedef __attribute__((address_space(3))) unsigned int lds_u32;
typedef __attribute__((address_space(1))) unsigned int glb_u32;

__device__ __forceinline__ float softplus_f(float x) {
  return fmaxf(x, 0.f) + log1pf(__expf(-fabsf(x)));
}
__device__ __forceinline__ float silu_f(float x) {
  return x / (1.f + __expf(-x));
}
__device__ __forceinline__ float bf2f(u16 v) {
  return __uint_as_float(((unsigned)v) << 16);
}
__device__ __forceinline__ u16 f2bf(float f) {
  unsigned u = __float_as_uint(f);
  u += 0x7FFFu + ((u >> 16) & 1u);
  return (u16)(u >> 16);
}

// ---------------------------------------------------------------------------
// Weight convert: fp32 W[K][N] -> bf16 Wt[Npad][K] (transposed, zero-padded)
// ---------------------------------------------------------------------------
struct WSeg { const float* src; u16* dst; int K, N, Npad; };
struct WAll { WSeg s[9]; };

__global__ __launch_bounds__(256) void wconv_k(WAll wa) {
  const WSeg w = wa.s[blockIdx.z];
  const int nb = blockIdx.x * 32, kb = blockIdx.y * 32;
  if (nb >= w.Npad || kb >= w.K) return;
  __shared__ float t[32][33];
  const int tx = threadIdx.x & 31, ty = threadIdx.x >> 5;
  for (int r = ty; r < 32; r += 8) {
    int k = kb + r, n = nb + tx;
    t[r][tx] = (n < w.N) ? w.src[(size_t)k * w.N + n] : 0.f;
  }
  __syncthreads();
  for (int r = ty; r < 32; r += 8) {
    int n = nb + r;
    w.dst[(size_t)n * w.K + kb + tx] = f2bf(t[tx][r]);
  }
}

// ---------------------------------------------------------------------------
// prep: chan-major fp32 (B,C,L) [+bias2[b][c]] -> token-major bf16 [B*L][C]
// ---------------------------------------------------------------------------
__global__ __launch_bounds__(256) void prep_bf_k(const float* __restrict__ x,
    const float* __restrict__ bias2, u16* __restrict__ out, int C) {
  const int l = blockIdx.x * 256 + threadIdx.x;
  const int b = blockIdx.y;
  const float* xb = x + (size_t)b * C * L + l;
  u16* ob = out + ((size_t)b * L + l) * C;
  for (int c0 = 0; c0 < C; c0 += 8) {
    union { u16 u[8]; int4 v; } t;
    #pragma unroll
    for (int j = 0; j < 8; ++j) {
      int c = c0 + j;
      float v = xb[(size_t)c * L];
      if (bias2) v += bias2[b * C + c];
      t.u[j] = f2bf(v);
    }
    *(int4*)(ob + c0) = t.v;
  }
}

// LayerNorm over C per token -> token-major bf16
__global__ __launch_bounds__(256) void ln_bf_k(const float* __restrict__ x,
    const float* __restrict__ g, const float* __restrict__ bb,
    u16* __restrict__ out, int C) {
  const int l = blockIdx.x * 256 + threadIdx.x;
  const int b = blockIdx.y;
  const float* xb = x + (size_t)b * C * L + l;
  float s = 0.f, sq = 0.f;
  for (int c = 0; c < C; ++c) { float v = xb[(size_t)c * L]; s += v; sq = fmaf(v, v, sq); }
  float m = s / C, var = sq / C - m * m;
  float rs = rsqrtf(var + 1e-5f);
  u16* ob = out + ((size_t)b * L + l) * C;
  for (int c0 = 0; c0 < C; c0 += 8) {
    union { u16 u[8]; int4 v; } t;
    #pragma unroll
    for (int j = 0; j < 8; ++j) {
      int c = c0 + j;
      float v = (xb[(size_t)c * L] - m) * rs * g[c] + bb[c];
      t.u[j] = f2bf(v);
    }
    *(int4*)(ob + c0) = t.v;
  }
}

// ---------------------------------------------------------------------------
// causal depthwise conv k=4 + bias + silu, token-major bf16 in/out
// ---------------------------------------------------------------------------
__global__ __launch_bounds__(256) void conv_bf_k(const u16* __restrict__ x,
    const float* __restrict__ w, const float* __restrict__ bias,
    u16* __restrict__ y, int C) {
  const int c = blockIdx.x * 64 + (threadIdx.x & 63);
  const int chunk = blockIdx.y * 4 + (threadIdx.x >> 6);
  const int T0 = chunk * 8;
  const float w0 = w[c * 4], w1 = w[c * 4 + 1], w2 = w[c * 4 + 2], w3 = w[c * 4 + 3];
  const float bs = bias[c];
  const bool first = (T0 & (L - 1)) == 0;
  float v[11];
  #pragma unroll
  for (int i = 0; i < 11; ++i) {
    if (i < 3 && first) v[i] = 0.f;
    else v[i] = bf2f(x[(size_t)(T0 - 3 + i) * C + c]);
  }
  #pragma unroll
  for (int j = 0; j < 8; ++j) {
    float s = bs + w0 * v[j] + w1 * v[j + 1] + w2 * v[j + 2] + w3 * v[j + 3];
    y[(size_t)(T0 + j) * C + c] = f2bf(silu_f(s));
  }
}

// ---------------------------------------------------------------------------
// MFMA bf16 GEMM: A [M=16384][K] token-major bf16 (optional concat A0|A1),
// Wt [Npad][K] bf16. Tile 128x128, 4 waves (2x2), BK=32, global_load_lds.
// LDS layout [kchunk][row][8] (k-chunk-major) -> conflict-light b128 reads.
// EPI: 0 fp32 row-major; 1 bf16 row-major; 2 chan-major fp32 + residual;
//      3 silu(x+bias) bf16; 4 (x+bias) bf16; 5 split bf16 (out0|out1).
// ---------------------------------------------------------------------------
struct MP {
  const u16 *A0, *A1, *Wt;
  const float *bias, *res;
  float* outF; u16 *outB0, *outB1;
  int K, K1, Nout, ldA, ldo, split;
};

template<int EPI>
__global__ __launch_bounds__(256) void mfma_gemm_k(MP p) {
  __shared__ u16 As[4096];
  __shared__ u16 Bs[4096];
  const int tid = threadIdx.x;
  const int lane = tid & 63;
  const int wid = tid >> 6;
  const int wm = wid >> 1, wn = wid & 1;
  const int n0 = blockIdx.x * 128;
  const int m0 = blockIdx.y * 128;
  const int srow = tid & 127;
  const int skc = tid >> 7;
  const int kgrp = lane >> 4, l16 = lane & 15;

  f32x4 acc[4][4];
  #pragma unroll
  for (int i = 0; i < 4; ++i)
    #pragma unroll
    for (int j = 0; j < 4; ++j)
      acc[i][j] = (f32x4){0.f, 0.f, 0.f, 0.f};

  for (int k0 = 0; k0 < p.K; k0 += 32) {
    const u16* Ab = p.A0;
    int kc = k0;
    if (p.A1 && k0 >= p.K1) { Ab = p.A1; kc = k0 - p.K1; }
    {
      const u16* g0 = Ab + (size_t)(m0 + srow) * p.ldA + kc + skc * 8;
      __builtin_amdgcn_global_load_lds((const glb_u32*)g0,
          (lds_u32*)(As + wid * 512), 16, 0, 0);
      __builtin_amdgcn_global_load_lds((const glb_u32*)(g0 + 16),
          (lds_u32*)(As + 2048 + wid * 512), 16, 0, 0);
      const u16* h0 = p.Wt + (size_t)(n0 + srow) * p.K + k0 + skc * 8;
      __builtin_amdgcn_global_load_lds((const glb_u32*)h0,
          (lds_u32*)(Bs + wid * 512), 16, 0, 0);
      __builtin_amdgcn_global_load_lds((const glb_u32*)(h0 + 16),
          (lds_u32*)(Bs + 2048 + wid * 512), 16, 0, 0);
    }
    __syncthreads();
    s16x8 af[4], bfr[4];
    #pragma unroll
    for (int mi = 0; mi < 4; ++mi)
      af[mi] = *(const s16x8*)(As + kgrp * 1024 + (wm * 64 + mi * 16 + l16) * 8);
    #pragma unroll
    for (int ni = 0; ni < 4; ++ni)
      bfr[ni] = *(const s16x8*)(Bs + kgrp * 1024 + (wn * 64 + ni * 16 + l16) * 8);
    #pragma unroll
    for (int mi = 0; mi < 4; ++mi)
      #pragma unroll
      for (int ni = 0; ni < 4; ++ni)
        acc[mi][ni] = __builtin_amdgcn_mfma_f32_16x16x32_bf16(af[mi], bfr[ni], acc[mi][ni], 0, 0, 0);
    __syncthreads();
  }

  if (EPI == 2) {
    #pragma unroll
    for (int mi = 0; mi < 4; ++mi) {
      int token = m0 + wm * 64 + mi * 16 + (lane >> 4) * 4;
      int b = token >> 12, l = token & (L - 1);
      #pragma unroll
      for (int ni = 0; ni < 4; ++ni) {
        int n = n0 + wn * 64 + ni * 16 + l16;
        if (n < p.Nout) {
          size_t o = ((size_t)b * p.Nout + n) * L + l;
          float4 r = *(const float4*)(p.res + o);
          float4 v = make_float4(acc[mi][ni][0] + r.x, acc[mi][ni][1] + r.y,
                                 acc[mi][ni][2] + r.z, acc[mi][ni][3] + r.w);
          *(float4*)(p.outF + o) = v;
        }
      }
    }
  } else {
    #pragma unroll
    for (int mi = 0; mi < 4; ++mi) {
      #pragma unroll
      for (int j = 0; j < 4; ++j) {
        int token = m0 + wm * 64 + mi * 16 + (lane >> 4) * 4 + j;
        #pragma unroll
        for (int ni = 0; ni < 4; ++ni) {
          int n = n0 + wn * 64 + ni * 16 + l16;
          float v = acc[mi][ni][j];
          if (EPI == 0) {
            if (n < p.Nout) p.outF[(size_t)token * p.ldo + n] = v;
          } else if (EPI == 1) {
            if (n < p.Nout) p.outB0[(size_t)token * p.ldo + n] = f2bf(v);
          } else if (EPI == 3) {
            if (n < p.Nout) p.outB0[(size_t)token * p.ldo + n] = f2bf(silu_f(v + p.bias[n]));
          } else if (EPI == 4) {
            if (n < p.Nout) p.outB0[(size_t)token * p.ldo + n] = f2bf(v + p.bias[n]);
          } else {  // 5: split
            if (n < p.split) p.outB0[(size_t)token * p.split + n] = f2bf(v);
            else p.outB1[(size_t)token * p.split + (n - p.split)] = f2bf(v);
          }
        }
      }
    }
  }
}

// ---------------------------------------------------------------------------
// small fp32 GEMM (dt projection): A row-major [M][lda], W fp32 [K][N],
// EPI: softplus(x + ebias[n]) -> fp32 row-major [M][N]
// ---------------------------------------------------------------------------
struct GemmP {
  const float* A0; const float* W; const float* ebias;
  float* out0;
  int K, N, lda, ldo;
};

__global__ __launch_bounds__(256) void gemm_f32_k(GemmP p) {
  __shared__ __align__(16) float As[16][64];
  __shared__ __align__(16) float Bs[16][64];
  const int tid = threadIdx.x;
  const int kidx = tid >> 4;
  const int li4 = (tid & 15) << 2;
  const int r0 = (tid & 15) << 2;
  const int c0 = (tid >> 4) << 2;
  const int n0 = blockIdx.x * 64;
  const int m0 = blockIdx.y * 64;
  float acc[4][4] = {};

  for (int k0 = 0; k0 < p.K; k0 += 16) {
    __syncthreads();
    {
      const int row = tid >> 2;
      const int kk4 = (tid & 3) << 2;
      const float* src = p.A0 + (size_t)(m0 + row) * p.lda;
      #pragma unroll
      for (int j = 0; j < 4; ++j) {
        int k = k0 + kk4 + j;
        As[kk4 + j][row] = (k < p.K) ? src[k] : 0.f;
      }
    }
    {
      int k = k0 + kidx;
      #pragma unroll
      for (int j = 0; j < 4; ++j) {
        int n = n0 + li4 + j;
        Bs[kidx][li4 + j] = (k < p.K && n < p.N) ? p.W[(size_t)k * p.N + n] : 0.f;
      }
    }
    __syncthreads();
    #pragma unroll
    for (int kk = 0; kk < 16; ++kk) {
      float4 a = *(const float4*)&As[kk][r0];
      float4 bq = *(const float4*)&Bs[kk][c0];
      float av[4] = {a.x, a.y, a.z, a.w};
      float bv[4] = {bq.x, bq.y, bq.z, bq.w};
      #pragma unroll
      for (int i = 0; i < 4; ++i)
        #pragma unroll
        for (int j = 0; j < 4; ++j)
          acc[i][j] = fmaf(av[i], bv[j], acc[i][j]);
    }
  }
  float eb[4] = {p.ebias[n0 + c0], p.ebias[n0 + c0 + 1], p.ebias[n0 + c0 + 2], p.ebias[n0 + c0 + 3]};
  #pragma unroll
  for (int i = 0; i < 4; ++i) {
    float4 v;
    v.x = softplus_f(acc[i][0] + eb[0]);
    v.y = softplus_f(acc[i][1] + eb[1]);
    v.z = softplus_f(acc[i][2] + eb[2]);
    v.w = softplus_f(acc[i][3] + eb[3]);
    *(float4*)&p.out0[(size_t)(m0 + r0 + i) * p.ldo + n0 + c0] = v;
  }
}

// ---------------------------------------------------------------------------
// Chunked selective scan, token-major. u,z,y bf16 [B*L][Dch]; dlt fp32;
// xdbl fp32 [B*L][64], B at roff.., C at roff+16..
// PF layout [c][slot 0..31][NCH] fp32: slots 0..15 = P, 16..31 = F/Hin.
// ---------------------------------------------------------------------------
template<int PASS>
__global__ __launch_bounds__(64) void scan_tm_k(
    const u16* __restrict__ u, const float* __restrict__ dlt,
    const float* __restrict__ Alog, const float* __restrict__ xdbl, int roff,
    const float* __restrict__ Dp, const u16* __restrict__ zT,
    float* __restrict__ PF, u16* __restrict__ yT,
    int Dch, int CLen, int NCH)
{
  const int d = blockIdx.x * 64 + threadIdx.x;
  const int c = blockIdx.y;
  const int b = blockIdx.z;
  const int ch = b * Dch + d;
  const size_t tok0 = (size_t)b * L + (size_t)c * CLen;
  float An[16], h[16], P[16];
  #pragma unroll
  for (int n = 0; n < 16; ++n) {
    An[n] = -__expf(Alog[d * 16 + n]);
    P[n] = 1.f; h[n] = 0.f;
  }
  if (PASS == 3) {
    #pragma unroll
    for (int n2 = 0; n2 < 16; ++n2)
      h[n2] = PF[((size_t)c * 32 + 16 + n2) * NCH + ch];
  }
  const float Dd = Dp[d];
  const u16* up = u + tok0 * Dch + d;
  const float* dp = dlt + tok0 * Dch + d;
  const u16* zp = zT + tok0 * Dch + d;
  u16* yr = yT + tok0 * Dch + d;
  const float* xr = xdbl + tok0 * 64 + roff;
  for (int t = 0; t < CLen; ++t) {
    const size_t od = (size_t)t * Dch;
    float dl = dp[od];
    float uu = bf2f(up[od]);
    float w = dl * uu;
    const float2* bp = (const float2*)(xr + (size_t)t * 64);
    float y = 0.f;
    #pragma unroll
    for (int q = 0; q < 8; ++q) {
      float2 bv = bp[q];
      float a0 = __expf(dl * An[2 * q]);
      float a1 = __expf(dl * An[2 * q + 1]);
      h[2 * q]     = fmaf(a0, h[2 * q],     w * bv.x);
      h[2 * q + 1] = fmaf(a1, h[2 * q + 1], w * bv.y);
      if (PASS == 1) {
        P[2 * q] *= a0; P[2 * q + 1] *= a1;
      } else {
        float2 cv = bp[q + 8];
        y = fmaf(h[2 * q], cv.x, y);
        y = fmaf(h[2 * q + 1], cv.y, y);
      }
    }
    if (PASS == 3) {
      float zv = bf2f(zp[od]);
      yr[od] = f2bf((y + Dd * uu) * silu_f(zv));
    }
  }
  if (PASS == 1) {
    #pragma unroll
    for (int n2 = 0; n2 < 16; ++n2) {
      PF[((size_t)c * 32 + n2) * NCH + ch] = P[n2];
      PF[((size_t)c * 32 + 16 + n2) * NCH + ch] = h[n2];
    }
  }
}

// Stitch: per (ch, state n) sequential over chunks; rewrites F slot with Hin.
__global__ __launch_bounds__(256) void stitch_k(float* __restrict__ PF,
    int NC, int NCH, int total) {
  int idx = blockIdx.x * 256 + threadIdx.x;
  if (idx >= total) return;
  int ch = idx % NCH, n = idx / NCH;
  float hin = 0.f;
  for (int c = 0; c < NC; ++c) {
    float* Ps = PF + ((size_t)c * 32 + n) * NCH + ch;
    float* Fs = PF + ((size_t)c * 32 + 16 + n) * NCH + ch;
    float Pv = *Ps, Fv = *Fs;
    *Fs = hin;
    hin = fmaf(Pv, hin, Fv);
  }
}

// ---------------------------------------------------------------------------
extern "C" void kernel_launch(void* const* d_in, const int* in_sizes, int n_in,
                              void* d_out, int out_size, void* d_ws, size_t ws_size,
                              hipStream_t stream) {
  const float* m_ll    = (const float*)d_in[0];
  const float* m_high  = (const float*)d_in[1];
  const float* zanc    = (const float*)d_in[2];
  const float* Kin     = (const float*)d_in[3];
  const float* Qin     = (const float*)d_in[4];
  const float* s_in_w  = (const float*)d_in[5];
  const float* s_conv_w= (const float*)d_in[6];
  const float* s_conv_b= (const float*)d_in[7];
  const float* s_x_w   = (const float*)d_in[8];
  const float* s_dt_w  = (const float*)d_in[9];
  const float* s_dt_b  = (const float*)d_in[10];
  const float* s_Alog  = (const float*)d_in[11];
  const float* s_D     = (const float*)d_in[12];
  const float* s_out_w = (const float*)d_in[13];
  const float* t_in_w  = (const float*)d_in[14];
  const float* t_conv_w= (const float*)d_in[15];
  const float* t_conv_b= (const float*)d_in[16];
  const float* t_kln_g = (const float*)d_in[17];
  const float* t_kln_b = (const float*)d_in[18];
  const float* t_k_w   = (const float*)d_in[19];
  const float* t_k_b   = (const float*)d_in[20];
  const float* t_qln_g = (const float*)d_in[21];
  const float* t_qln_b = (const float*)d_in[22];
  const float* t_q_w   = (const float*)d_in[23];
  const float* t_q_b   = (const float*)d_in[24];
  const float* t_dtbc_w= (const float*)d_in[25];
  const float* t_dt_w  = (const float*)d_in[26];
  const float* t_dt_b  = (const float*)d_in[27];
  const float* t_gate_w= (const float*)d_in[28];
  const float* t_gate_b= (const float*)d_in[29];
  const float* t_Alog  = (const float*)d_in[30];
  const float* t_D     = (const float*)d_in[31];
  const float* t_out_w = (const float*)d_in[32];

  float* out1 = (float*)d_out;               // (4, 96, 4096)  = 1,572,864 f
  float* out2 = out1 + (size_t)4 * 96 * L;   // (4, 288, 4096) = 4,718,592 f
  float* ws = (float*)d_ws;

  // Weight region (bf16, persistent across call)
  u16* w_sin   = (u16*)(ws + 0);        // [384][96]
  u16* w_sx    = (u16*)(ws + 18432);    // [128][192]
  u16* w_sout  = (u16*)(ws + 30720);    // [128][192]
  u16* w_tin   = (u16*)(ws + 43008);    // [640][288]
  u16* w_tk    = (u16*)(ws + 135168);   // [640][288]
  u16* w_tq    = (u16*)(ws + 227328);   // [640][288]
  u16* w_tdtbc = (u16*)(ws + 319488);   // [128][1152]
  u16* w_tgate = (u16*)(ws + 393216);   // [640][1152]
  u16* w_tout  = (u16*)(ws + 761856);   // [384][576]
  // Big slots (float offsets)
  float* SA = ws + 872448;    // 4,718,592 f
  float* SB = ws + 5591040;   // 4,718,592 f
  float* SC = ws + 10309632;  // 4,718,592 f
  float* SD = ws + 15028224;  // 4,718,592 f
  float* SE = ws + 19746816;  // 4,718,592 f
  float* SF = ws + 24465408;  // 1,048,576 f
  float* SG = ws + 25513984;  // 2,359,296 f

  dim3 blk(256);
  dim3 blk64(64);

  // ---- weight conversion (9 segments) ----
  {
    WAll wa;
    wa.s[0] = {s_in_w,   w_sin,    96, 384, 384};
    wa.s[1] = {s_x_w,    w_sx,    192,  38, 128};
    wa.s[2] = {s_out_w,  w_sout,  192,  96, 128};
    wa.s[3] = {t_in_w,   w_tin,   288, 576, 640};
    wa.s[4] = {t_k_w,    w_tk,    288, 576, 640};
    wa.s[5] = {t_q_w,    w_tq,    288, 576, 640};
    wa.s[6] = {t_dtbc_w, w_tdtbc, 1152, 50, 128};
    wa.s[7] = {t_gate_w, w_tgate, 1152, 576, 640};
    wa.s[8] = {t_out_w,  w_tout,  576, 288, 384};
    wconv_k<<<dim3(20, 36, 9), blk, 0, stream>>>(wa);
  }

  // ================= SSS stream =================
  u16* a_ll  = (u16*)SG;                  // [16384][96]
  u16* x_in  = (u16*)SA;                  // [16384][192]
  u16* zTs   = (u16*)(SA + 1572864);      // [16384][192]
  u16* xc    = (u16*)SB;                  // [16384][192]
  float* xdbl = SF;                       // [16384][64]
  float* dlt  = SC;                       // [16384][192] fp32
  u16* y_bf  = (u16*)SD;                  // [16384][192]
  float* PFs  = SE;                       // 128*32*768

  prep_bf_k<<<dim3(16, 4), blk, 0, stream>>>(m_ll, zanc, a_ll, 96);
  { MP p{}; p.A0 = a_ll; p.Wt = w_sin; p.K = 96; p.K1 = 1 << 28; p.Nout = 384;
    p.ldA = 96; p.split = 192; p.outB0 = x_in; p.outB1 = zTs;
    mfma_gemm_k<5><<<dim3(3, 128), blk, 0, stream>>>(p); }
  conv_bf_k<<<dim3(3, 512), blk, 0, stream>>>(x_in, s_conv_w, s_conv_b, xc, 192);
  { MP p{}; p.A0 = xc; p.Wt = w_sx; p.K = 192; p.K1 = 1 << 28; p.Nout = 64;
    p.ldA = 192; p.ldo = 64; p.outF = xdbl;
    mfma_gemm_k<0><<<dim3(1, 128), blk, 0, stream>>>(p); }
  { GemmP p{}; p.A0 = xdbl; p.lda = 64; p.K = 6; p.W = s_dt_w; p.N = 192;
    p.ebias = s_dt_b; p.out0 = dlt; p.ldo = 192;
    gemm_f32_k<<<dim3(3, 256), blk, 0, stream>>>(p); }
  scan_tm_k<1><<<dim3(3, 128, 4), blk64, 0, stream>>>(xc, dlt, s_Alog, xdbl, 6, s_D, zTs, PFs, y_bf, 192, 32, 768);
  stitch_k<<<dim3(48), blk, 0, stream>>>(PFs, 128, 768, 12288);
  scan_tm_k<3><<<dim3(3, 128, 4), blk64, 0, stream>>>(xc, dlt, s_Alog, xdbl, 6, s_D, zTs, PFs, y_bf, 192, 32, 768);
  { MP p{}; p.A0 = y_bf; p.Wt = w_sout; p.K = 192; p.K1 = 1 << 28; p.Nout = 96;
    p.ldA = 192; p.res = m_ll; p.outF = out1;
    mfma_gemm_k<2><<<dim3(1, 128), blk, 0, stream>>>(p); }

  // ================= STS stream =================
  u16* a_hi  = (u16*)SG;                  // [16384][288] (also aK/aQ slot)
  u16* xin3  = (u16*)SA;                  // [16384][576]
  u16* xc3   = (u16*)SB;                  // [16384][576]
  u16* kp    = (u16*)SC;                  // [16384][576]
  u16* qp    = (u16*)SD;                  // [16384][576]
  float* dlt3 = SC;                       // [16384][576] fp32 (over kp+qp)
  u16* zg3   = (u16*)SE;                  // [16384][576]
  float* xdbl3 = SF;                      // [16384][64]
  u16* y3    = (u16*)SA;                  // [16384][576] (over xin3)
  float* PFt = out2;                      // 64*32*2304 == |out2|

  prep_bf_k<<<dim3(16, 4), blk, 0, stream>>>(m_high, nullptr, a_hi, 288);
  { MP p{}; p.A0 = a_hi; p.Wt = w_tin; p.K = 288; p.K1 = 1 << 28; p.Nout = 576;
    p.ldA = 288; p.ldo = 576; p.outB0 = xin3;
    mfma_gemm_k<1><<<dim3(5, 128), blk, 0, stream>>>(p); }
  conv_bf_k<<<dim3(9, 512), blk, 0, stream>>>(xin3, t_conv_w, t_conv_b, xc3, 576);
  ln_bf_k<<<dim3(16, 4), blk, 0, stream>>>(Kin, t_kln_g, t_kln_b, a_hi, 288);
  { MP p{}; p.A0 = a_hi; p.Wt = w_tk; p.K = 288; p.K1 = 1 << 28; p.Nout = 576;
    p.ldA = 288; p.ldo = 576; p.bias = t_k_b; p.outB0 = kp;
    mfma_gemm_k<3><<<dim3(5, 128), blk, 0, stream>>>(p); }
  ln_bf_k<<<dim3(16, 4), blk, 0, stream>>>(Qin, t_qln_g, t_qln_b, a_hi, 288);
  { MP p{}; p.A0 = a_hi; p.Wt = w_tq; p.K = 288; p.K1 = 1 << 28; p.Nout = 576;
    p.ldA = 288; p.ldo = 576; p.bias = t_q_b; p.outB0 = qp;
    mfma_gemm_k<3><<<dim3(5, 128), blk, 0, stream>>>(p); }
  { MP p{}; p.A0 = xc3; p.A1 = kp; p.Wt = w_tdtbc; p.K = 1152; p.K1 = 576;
    p.Nout = 64; p.ldA = 576; p.ldo = 64; p.outF = xdbl3;
    mfma_gemm_k<0><<<dim3(1, 128), blk, 0, stream>>>(p); }
  { MP p{}; p.A0 = xc3; p.A1 = qp; p.Wt = w_tgate; p.K = 1152; p.K1 = 576;
    p.Nout = 576; p.ldA = 576; p.ldo = 576; p.bias = t_gate_b; p.outB0 = zg3;
    mfma_gemm_k<4><<<dim3(5, 128), blk, 0, stream>>>(p); }
  { GemmP p{}; p.A0 = xdbl3; p.lda = 64; p.K = 18; p.W = t_dt_w; p.N = 576;
    p.ebias = t_dt_b; p.out0 = dlt3; p.ldo = 576;
    gemm_f32_k<<<dim3(9, 256), blk, 0, stream>>>(p); }
  scan_tm_k<1><<<dim3(9, 64, 4), blk64, 0, stream>>>(xc3, dlt3, t_Alog, xdbl3, 18, t_D, zg3, PFt, y3, 576, 64, 2304);
  stitch_k<<<dim3(144), blk, 0, stream>>>(PFt, 64, 2304, 36864);
  scan_tm_k<3><<<dim3(9, 64, 4), blk64, 0, stream>>>(xc3, dlt3, t_Alog, xdbl3, 18, t_D, zg3, PFt, y3, 576, 64, 2304);
  { MP p{}; p.A0 = y3; p.Wt = w_tout; p.K = 576; p.K1 = 1 << 28; p.Nout = 288;
    p.ldA = 576; p.res = m_high; p.outF = out2;
    mfma_gemm_k<2><<<dim3(3, 128), blk, 0, stream>>>(p); }
}

// Round 4
// 603.365 us; speedup vs baseline: 4.8700x; 1.3755x over previous
//
#include <hip/hip_runtime.h>
#include <math.h>

// DualStreamBlock: B=4, DIM=96, DIM3=288, H=W=64, L=4096, DSTATE=16
// di=192, di3=576, r=6, r3=18
#define L 4096

typedef unsigned short u16;
typedef float f32x4 __attribute__((ext_vector_type(4)));
typedef short s16x8 __attribute__((ext_vector_type(8)));
typedef __attribute__((address_space(3))) unsigned int lds_u32;
typedef __attribute__((address_space(1))) unsigned int glb_u32;

__device__ __forceinline__ float softplus_f(float x) {
  return fmaxf(x, 0.f) + log1pf(__expf(-fabsf(x)));
}
__device__ __forceinline__ float silu_f(float x) {
  return x / (1.f + __expf(-x));
}
__device__ __forceinline__ float bf2f(u16 v) {
  return __uint_as_float(((unsigned)v) << 16);
}
__device__ __forceinline__ u16 f2bf(float f) {
  unsigned u = __float_as_uint(f);
  u += 0x7FFFu + ((u >> 16) & 1u);
  return (u16)(u >> 16);
}

// ---------------------------------------------------------------------------
// Weight convert: fp32 W[K][N] -> bf16 Wt[Npad][K] (transposed, zero-padded)
// ---------------------------------------------------------------------------
struct WSeg { const float* src; u16* dst; int K, N, Npad; };
struct WAll { WSeg s[9]; };

__global__ __launch_bounds__(256) void wconv_k(WAll wa) {
  const WSeg w = wa.s[blockIdx.z];
  const int nb = blockIdx.x * 32, kb = blockIdx.y * 32;
  if (nb >= w.Npad || kb >= w.K) return;
  __shared__ float t[32][33];
  const int tx = threadIdx.x & 31, ty = threadIdx.x >> 5;
  for (int r = ty; r < 32; r += 8) {
    int k = kb + r, n = nb + tx;
    t[r][tx] = (n < w.N) ? w.src[(size_t)k * w.N + n] : 0.f;
  }
  __syncthreads();
  for (int r = ty; r < 32; r += 8) {
    int n = nb + r;
    w.dst[(size_t)n * w.K + kb + tx] = f2bf(t[tx][r]);
  }
}

// ---------------------------------------------------------------------------
// Tiled transpose prep: chan-major fp32 (B,C,L) -> token-major bf16 [B*L][C]
// DO_LN=1: LayerNorm over C (gamma/beta). DO_LN=0: optional +bias2[b*C+c].
// Tile = 32 tokens x C. Coalesced global loads along l, packed int4 stores.
// ---------------------------------------------------------------------------
template<int DO_LN>
__global__ __launch_bounds__(256) void trans_bf_k(
    const float* __restrict__ x, const float* __restrict__ gam,
    const float* __restrict__ bet, const float* __restrict__ bias2,
    u16* __restrict__ out, int C) {
  __shared__ float tile[288][33];
  __shared__ float psum[8][32], psq[8][32];
  __shared__ float mm[32], rr[32];
  const int tid = threadIdx.x;
  const int l0 = blockIdx.x * 32;
  const int b = blockIdx.y;
  const int lane32 = tid & 31, row8 = tid >> 5;
  const float* xb = x + (size_t)b * C * L + l0;

  for (int c = row8; c < C; c += 8)
    tile[c][lane32] = xb[(size_t)c * L + lane32];
  __syncthreads();

  if (DO_LN) {
    float s = 0.f, sq = 0.f;
    for (int c = row8; c < C; c += 8) {
      float v = tile[c][lane32];
      s += v; sq = fmaf(v, v, sq);
    }
    psum[row8][lane32] = s; psq[row8][lane32] = sq;
    __syncthreads();
    if (row8 == 0) {
      float ts = 0.f, tq = 0.f;
      #pragma unroll
      for (int g = 0; g < 8; ++g) { ts += psum[g][lane32]; tq += psq[g][lane32]; }
      float m = ts / C;
      float var = tq / C - m * m;
      mm[lane32] = m;
      rr[lane32] = rsqrtf(var + 1e-5f);
    }
    __syncthreads();
  }

  u16* ob = out + ((size_t)b * L + l0) * C;
  const int total = 32 * C;
  for (int o = tid * 8; o < total; o += 2048) {
    int t = o / C, c = o % C;
    float m = 0.f, rs = 0.f;
    if (DO_LN) { m = mm[t]; rs = rr[t]; }
    union { u16 u[8]; int4 v; } pk;
    #pragma unroll
    for (int j = 0; j < 8; ++j) {
      float v = tile[c + j][t];
      if (DO_LN) v = (v - m) * rs * gam[c + j] + bet[c + j];
      else if (bias2) v += bias2[b * C + c + j];
      pk.u[j] = f2bf(v);
    }
    *(int4*)(ob + o) = pk.v;
  }
}

// ---------------------------------------------------------------------------
// causal depthwise conv k=4 + bias + silu, token-major bf16 in/out
// ---------------------------------------------------------------------------
__global__ __launch_bounds__(256) void conv_bf_k(const u16* __restrict__ x,
    const float* __restrict__ w, const float* __restrict__ bias,
    u16* __restrict__ y, int C) {
  const int c = blockIdx.x * 64 + (threadIdx.x & 63);
  const int chunk = blockIdx.y * 4 + (threadIdx.x >> 6);
  const int T0 = chunk * 8;
  const float w0 = w[c * 4], w1 = w[c * 4 + 1], w2 = w[c * 4 + 2], w3 = w[c * 4 + 3];
  const float bs = bias[c];
  const bool first = (T0 & (L - 1)) == 0;
  float v[11];
  #pragma unroll
  for (int i = 0; i < 11; ++i) {
    if (i < 3 && first) v[i] = 0.f;
    else v[i] = bf2f(x[(size_t)(T0 - 3 + i) * C + c]);
  }
  #pragma unroll
  for (int j = 0; j < 8; ++j) {
    float s = bs + w0 * v[j] + w1 * v[j + 1] + w2 * v[j + 2] + w3 * v[j + 3];
    y[(size_t)(T0 + j) * C + c] = f2bf(silu_f(s));
  }
}

// ---------------------------------------------------------------------------
// MFMA bf16 GEMM: A [M=16384][K] token-major bf16 (optional concat A0|A1),
// Wt [Npad][K] bf16. Tile 128x128, 4 waves (2x2), BK=32, global_load_lds.
// EPI: 0 fp32 row-major; 1 bf16 row-major; 2 chan-major fp32 + residual;
//      3 silu(x+bias) bf16; 4 (x+bias) bf16; 5 split bf16 (out0|out1).
// ---------------------------------------------------------------------------
struct MP {
  const u16 *A0, *A1, *Wt;
  const float *bias, *res;
  float* outF; u16 *outB0, *outB1;
  int K, K1, Nout, ldA, ldo, split;
};

template<int EPI>
__global__ __launch_bounds__(256) void mfma_gemm_k(MP p) {
  __shared__ u16 As[4096];
  __shared__ u16 Bs[4096];
  const int tid = threadIdx.x;
  const int lane = tid & 63;
  const int wid = tid >> 6;
  const int wm = wid >> 1, wn = wid & 1;
  const int n0 = blockIdx.x * 128;
  const int m0 = blockIdx.y * 128;
  const int srow = tid & 127;
  const int skc = tid >> 7;
  const int kgrp = lane >> 4, l16 = lane & 15;

  f32x4 acc[4][4];
  #pragma unroll
  for (int i = 0; i < 4; ++i)
    #pragma unroll
    for (int j = 0; j < 4; ++j)
      acc[i][j] = (f32x4){0.f, 0.f, 0.f, 0.f};

  for (int k0 = 0; k0 < p.K; k0 += 32) {
    const u16* Ab = p.A0;
    int kc = k0;
    if (p.A1 && k0 >= p.K1) { Ab = p.A1; kc = k0 - p.K1; }
    {
      const u16* g0 = Ab + (size_t)(m0 + srow) * p.ldA + kc + skc * 8;
      __builtin_amdgcn_global_load_lds((const glb_u32*)g0,
          (lds_u32*)(As + wid * 512), 16, 0, 0);
      __builtin_amdgcn_global_load_lds((const glb_u32*)(g0 + 16),
          (lds_u32*)(As + 2048 + wid * 512), 16, 0, 0);
      const u16* h0 = p.Wt + (size_t)(n0 + srow) * p.K + k0 + skc * 8;
      __builtin_amdgcn_global_load_lds((const glb_u32*)h0,
          (lds_u32*)(Bs + wid * 512), 16, 0, 0);
      __builtin_amdgcn_global_load_lds((const glb_u32*)(h0 + 16),
          (lds_u32*)(Bs + 2048 + wid * 512), 16, 0, 0);
    }
    __syncthreads();
    s16x8 af[4], bfr[4];
    #pragma unroll
    for (int mi = 0; mi < 4; ++mi)
      af[mi] = *(const s16x8*)(As + kgrp * 1024 + (wm * 64 + mi * 16 + l16) * 8);
    #pragma unroll
    for (int ni = 0; ni < 4; ++ni)
      bfr[ni] = *(const s16x8*)(Bs + kgrp * 1024 + (wn * 64 + ni * 16 + l16) * 8);
    #pragma unroll
    for (int mi = 0; mi < 4; ++mi)
      #pragma unroll
      for (int ni = 0; ni < 4; ++ni)
        acc[mi][ni] = __builtin_amdgcn_mfma_f32_16x16x32_bf16(af[mi], bfr[ni], acc[mi][ni], 0, 0, 0);
    __syncthreads();
  }

  if (EPI == 2) {
    #pragma unroll
    for (int mi = 0; mi < 4; ++mi) {
      int token = m0 + wm * 64 + mi * 16 + (lane >> 4) * 4;
      int b = token >> 12, l = token & (L - 1);
      #pragma unroll
      for (int ni = 0; ni < 4; ++ni) {
        int n = n0 + wn * 64 + ni * 16 + l16;
        if (n < p.Nout) {
          size_t o = ((size_t)b * p.Nout + n) * L + l;
          float4 r = *(const float4*)(p.res + o);
          float4 v = make_float4(acc[mi][ni][0] + r.x, acc[mi][ni][1] + r.y,
                                 acc[mi][ni][2] + r.z, acc[mi][ni][3] + r.w);
          *(float4*)(p.outF + o) = v;
        }
      }
    }
  } else {
    #pragma unroll
    for (int mi = 0; mi < 4; ++mi) {
      #pragma unroll
      for (int j = 0; j < 4; ++j) {
        int token = m0 + wm * 64 + mi * 16 + (lane >> 4) * 4 + j;
        #pragma unroll
        for (int ni = 0; ni < 4; ++ni) {
          int n = n0 + wn * 64 + ni * 16 + l16;
          float v = acc[mi][ni][j];
          if (EPI == 0) {
            if (n < p.Nout) p.outF[(size_t)token * p.ldo + n] = v;
          } else if (EPI == 1) {
            if (n < p.Nout) p.outB0[(size_t)token * p.ldo + n] = f2bf(v);
          } else if (EPI == 3) {
            if (n < p.Nout) p.outB0[(size_t)token * p.ldo + n] = f2bf(silu_f(v + p.bias[n]));
          } else if (EPI == 4) {
            if (n < p.Nout) p.outB0[(size_t)token * p.ldo + n] = f2bf(v + p.bias[n]);
          } else {  // 5: split
            if (n < p.split) p.outB0[(size_t)token * p.split + n] = f2bf(v);
            else p.outB1[(size_t)token * p.split + (n - p.split)] = f2bf(v);
          }
        }
      }
    }
  }
}

// ---------------------------------------------------------------------------
// small fp32 GEMM (dt projection): A row-major [M][lda], W fp32 [K][N],
// EPI: softplus(x + ebias[n]) -> fp32 row-major [M][N]
// ---------------------------------------------------------------------------
struct GemmP {
  const float* A0; const float* W; const float* ebias;
  float* out0;
  int K, N, lda, ldo;
};

__global__ __launch_bounds__(256) void gemm_f32_k(GemmP p) {
  __shared__ __align__(16) float As[16][64];
  __shared__ __align__(16) float Bs[16][64];
  const int tid = threadIdx.x;
  const int kidx = tid >> 4;
  const int li4 = (tid & 15) << 2;
  const int r0 = (tid & 15) << 2;
  const int c0 = (tid >> 4) << 2;
  const int n0 = blockIdx.x * 64;
  const int m0 = blockIdx.y * 64;
  float acc[4][4] = {};

  for (int k0 = 0; k0 < p.K; k0 += 16) {
    __syncthreads();
    {
      const int row = tid >> 2;
      const int kk4 = (tid & 3) << 2;
      const float* src = p.A0 + (size_t)(m0 + row) * p.lda;
      #pragma unroll
      for (int j = 0; j < 4; ++j) {
        int k = k0 + kk4 + j;
        As[kk4 + j][row] = (k < p.K) ? src[k] : 0.f;
      }
    }
    {
      int k = k0 + kidx;
      #pragma unroll
      for (int j = 0; j < 4; ++j) {
        int n = n0 + li4 + j;
        Bs[kidx][li4 + j] = (k < p.K && n < p.N) ? p.W[(size_t)k * p.N + n] : 0.f;
      }
    }
    __syncthreads();
    #pragma unroll
    for (int kk = 0; kk < 16; ++kk) {
      float4 a = *(const float4*)&As[kk][r0];
      float4 bq = *(const float4*)&Bs[kk][c0];
      float av[4] = {a.x, a.y, a.z, a.w};
      float bv[4] = {bq.x, bq.y, bq.z, bq.w};
      #pragma unroll
      for (int i = 0; i < 4; ++i)
        #pragma unroll
        for (int j = 0; j < 4; ++j)
          acc[i][j] = fmaf(av[i], bv[j], acc[i][j]);
    }
  }
  float eb[4] = {p.ebias[n0 + c0], p.ebias[n0 + c0 + 1], p.ebias[n0 + c0 + 2], p.ebias[n0 + c0 + 3]};
  #pragma unroll
  for (int i = 0; i < 4; ++i) {
    float4 v;
    v.x = softplus_f(acc[i][0] + eb[0]);
    v.y = softplus_f(acc[i][1] + eb[1]);
    v.z = softplus_f(acc[i][2] + eb[2]);
    v.w = softplus_f(acc[i][3] + eb[3]);
    *(float4*)&p.out0[(size_t)(m0 + r0 + i) * p.ldo + n0 + c0] = v;
  }
}

// ---------------------------------------------------------------------------
// Chunked selective scan, token-major. u,z,y bf16 [B*L][Dch]; dlt fp32;
// xdbl fp32 [B*L][64], B at roff.., C at roff+16..
// PF layout [c][slot 0..31][NCH] fp32: slots 0..15 = P, 16..31 = F/Hin.
// ---------------------------------------------------------------------------
template<int PASS>
__global__ __launch_bounds__(64) void scan_tm_k(
    const u16* __restrict__ u, const float* __restrict__ dlt,
    const float* __restrict__ Alog, const float* __restrict__ xdbl, int roff,
    const float* __restrict__ Dp, const u16* __restrict__ zT,
    float* __restrict__ PF, u16* __restrict__ yT,
    int Dch, int CLen, int NCH)
{
  const int d = blockIdx.x * 64 + threadIdx.x;
  const int c = blockIdx.y;
  const int b = blockIdx.z;
  const int ch = b * Dch + d;
  const size_t tok0 = (size_t)b * L + (size_t)c * CLen;
  float An[16], h[16], P[16];
  #pragma unroll
  for (int n = 0; n < 16; ++n) {
    An[n] = -__expf(Alog[d * 16 + n]);
    P[n] = 1.f; h[n] = 0.f;
  }
  if (PASS == 3) {
    #pragma unroll
    for (int n2 = 0; n2 < 16; ++n2)
      h[n2] = PF[((size_t)c * 32 + 16 + n2) * NCH + ch];
  }
  const float Dd = Dp[d];
  const u16* up = u + tok0 * Dch + d;
  const float* dp = dlt + tok0 * Dch + d;
  const u16* zp = zT + tok0 * Dch + d;
  u16* yr = yT + tok0 * Dch + d;
  const float* xr = xdbl + tok0 * 64 + roff;
  for (int t = 0; t < CLen; ++t) {
    const size_t od = (size_t)t * Dch;
    float dl = dp[od];
    float uu = bf2f(up[od]);
    float w = dl * uu;
    const float2* bp = (const float2*)(xr + (size_t)t * 64);
    float y = 0.f;
    #pragma unroll
    for (int q = 0; q < 8; ++q) {
      float2 bv = bp[q];
      float a0 = __expf(dl * An[2 * q]);
      float a1 = __expf(dl * An[2 * q + 1]);
      h[2 * q]     = fmaf(a0, h[2 * q],     w * bv.x);
      h[2 * q + 1] = fmaf(a1, h[2 * q + 1], w * bv.y);
      if (PASS == 1) {
        P[2 * q] *= a0; P[2 * q + 1] *= a1;
      } else {
        float2 cv = bp[q + 8];
        y = fmaf(h[2 * q], cv.x, y);
        y = fmaf(h[2 * q + 1], cv.y, y);
      }
    }
    if (PASS == 3) {
      float zv = bf2f(zp[od]);
      yr[od] = f2bf((y + Dd * uu) * silu_f(zv));
    }
  }
  if (PASS == 1) {
    #pragma unroll
    for (int n2 = 0; n2 < 16; ++n2) {
      PF[((size_t)c * 32 + n2) * NCH + ch] = P[n2];
      PF[((size_t)c * 32 + 16 + n2) * NCH + ch] = h[n2];
    }
  }
}

// Stitch: per (ch, state n) sequential over chunks; rewrites F slot with Hin.
__global__ __launch_bounds__(256) void stitch_k(float* __restrict__ PF,
    int NC, int NCH, int total) {
  int idx = blockIdx.x * 256 + threadIdx.x;
  if (idx >= total) return;
  int ch = idx % NCH, n = idx / NCH;
  float hin = 0.f;
  for (int c = 0; c < NC; ++c) {
    float* Ps = PF + ((size_t)c * 32 + n) * NCH + ch;
    float* Fs = PF + ((size_t)c * 32 + 16 + n) * NCH + ch;
    float Pv = *Ps, Fv = *Fs;
    *Fs = hin;
    hin = fmaf(Pv, hin, Fv);
  }
}

// ---------------------------------------------------------------------------
extern "C" void kernel_launch(void* const* d_in, const int* in_sizes, int n_in,
                              void* d_out, int out_size, void* d_ws, size_t ws_size,
                              hipStream_t stream) {
  const float* m_ll    = (const float*)d_in[0];
  const float* m_high  = (const float*)d_in[1];
  const float* zanc    = (const float*)d_in[2];
  const float* Kin     = (const float*)d_in[3];
  const float* Qin     = (const float*)d_in[4];
  const float* s_in_w  = (const float*)d_in[5];
  const float* s_conv_w= (const float*)d_in[6];
  const float* s_conv_b= (const float*)d_in[7];
  const float* s_x_w   = (const float*)d_in[8];
  const float* s_dt_w  = (const float*)d_in[9];
  const float* s_dt_b  = (const float*)d_in[10];
  const float* s_Alog  = (const float*)d_in[11];
  const float* s_D     = (const float*)d_in[12];
  const float* s_out_w = (const float*)d_in[13];
  const float* t_in_w  = (const float*)d_in[14];
  const float* t_conv_w= (const float*)d_in[15];
  const float* t_conv_b= (const float*)d_in[16];
  const float* t_kln_g = (const float*)d_in[17];
  const float* t_kln_b = (const float*)d_in[18];
  const float* t_k_w   = (const float*)d_in[19];
  const float* t_k_b   = (const float*)d_in[20];
  const float* t_qln_g = (const float*)d_in[21];
  const float* t_qln_b = (const float*)d_in[22];
  const float* t_q_w   = (const float*)d_in[23];
  const float* t_q_b   = (const float*)d_in[24];
  const float* t_dtbc_w= (const float*)d_in[25];
  const float* t_dt_w  = (const float*)d_in[26];
  const float* t_dt_b  = (const float*)d_in[27];
  const float* t_gate_w= (const float*)d_in[28];
  const float* t_gate_b= (const float*)d_in[29];
  const float* t_Alog  = (const float*)d_in[30];
  const float* t_D     = (const float*)d_in[31];
  const float* t_out_w = (const float*)d_in[32];

  float* out1 = (float*)d_out;               // (4, 96, 4096)  = 1,572,864 f
  float* out2 = out1 + (size_t)4 * 96 * L;   // (4, 288, 4096) = 4,718,592 f
  float* ws = (float*)d_ws;

  // Weight region (bf16)
  u16* w_sin   = (u16*)(ws + 0);        // [384][96]
  u16* w_sx    = (u16*)(ws + 18432);    // [128][192]
  u16* w_sout  = (u16*)(ws + 30720);    // [128][192]
  u16* w_tin   = (u16*)(ws + 43008);    // [640][288]
  u16* w_tk    = (u16*)(ws + 135168);   // [640][288]
  u16* w_tq    = (u16*)(ws + 227328);   // [640][288]
  u16* w_tdtbc = (u16*)(ws + 319488);   // [128][1152]
  u16* w_tgate = (u16*)(ws + 393216);   // [640][1152]
  u16* w_tout  = (u16*)(ws + 761856);   // [384][576]
  // Big slots (float offsets)
  float* SA = ws + 872448;    // 4,718,592 f
  float* SB = ws + 5591040;   // 4,718,592 f
  float* SC = ws + 10309632;  // 4,718,592 f
  float* SD = ws + 15028224;  // 4,718,592 f
  float* SE = ws + 19746816;  // 4,718,592 f
  float* SF = ws + 24465408;  // 1,048,576 f
  float* SG = ws + 25513984;  // 2,359,296 f

  dim3 blk(256);
  dim3 blk64(64);
  dim3 tgrid(128, 4);

  // ---- weight conversion (9 segments) ----
  {
    WAll wa;
    wa.s[0] = {s_in_w,   w_sin,    96, 384, 384};
    wa.s[1] = {s_x_w,    w_sx,    192,  38, 128};
    wa.s[2] = {s_out_w,  w_sout,  192,  96, 128};
    wa.s[3] = {t_in_w,   w_tin,   288, 576, 640};
    wa.s[4] = {t_k_w,    w_tk,    288, 576, 640};
    wa.s[5] = {t_q_w,    w_tq,    288, 576, 640};
    wa.s[6] = {t_dtbc_w, w_tdtbc, 1152, 50, 128};
    wa.s[7] = {t_gate_w, w_tgate, 1152, 576, 640};
    wa.s[8] = {t_out_w,  w_tout,  576, 288, 384};
    wconv_k<<<dim3(20, 36, 9), blk, 0, stream>>>(wa);
  }

  // ================= SSS stream =================
  u16* a_ll  = (u16*)SG;                  // [16384][96]
  u16* x_in  = (u16*)SA;                  // [16384][192]
  u16* zTs   = (u16*)(SA + 1572864);      // [16384][192]
  u16* xc    = (u16*)SB;                  // [16384][192]
  float* xdbl = SF;                       // [16384][64]
  float* dlt  = SC;                       // [16384][192] fp32
  u16* y_bf  = (u16*)SD;                  // [16384][192]
  float* PFs  = SE;                       // 128*32*768

  trans_bf_k<0><<<tgrid, blk, 0, stream>>>(m_ll, nullptr, nullptr, zanc, a_ll, 96);
  { MP p{}; p.A0 = a_ll; p.Wt = w_sin; p.K = 96; p.K1 = 1 << 28; p.Nout = 384;
    p.ldA = 96; p.split = 192; p.outB0 = x_in; p.outB1 = zTs;
    mfma_gemm_k<5><<<dim3(3, 128), blk, 0, stream>>>(p); }
  conv_bf_k<<<dim3(3, 512), blk, 0, stream>>>(x_in, s_conv_w, s_conv_b, xc, 192);
  { MP p{}; p.A0 = xc; p.Wt = w_sx; p.K = 192; p.K1 = 1 << 28; p.Nout = 64;
    p.ldA = 192; p.ldo = 64; p.outF = xdbl;
    mfma_gemm_k<0><<<dim3(1, 128), blk, 0, stream>>>(p); }
  { GemmP p{}; p.A0 = xdbl; p.lda = 64; p.K = 6; p.W = s_dt_w; p.N = 192;
    p.ebias = s_dt_b; p.out0 = dlt; p.ldo = 192;
    gemm_f32_k<<<dim3(3, 256), blk, 0, stream>>>(p); }
  scan_tm_k<1><<<dim3(3, 128, 4), blk64, 0, stream>>>(xc, dlt, s_Alog, xdbl, 6, s_D, zTs, PFs, y_bf, 192, 32, 768);
  stitch_k<<<dim3(48), blk, 0, stream>>>(PFs, 128, 768, 12288);
  scan_tm_k<3><<<dim3(3, 128, 4), blk64, 0, stream>>>(xc, dlt, s_Alog, xdbl, 6, s_D, zTs, PFs, y_bf, 192, 32, 768);
  { MP p{}; p.A0 = y_bf; p.Wt = w_sout; p.K = 192; p.K1 = 1 << 28; p.Nout = 96;
    p.ldA = 192; p.res = m_ll; p.outF = out1;
    mfma_gemm_k<2><<<dim3(1, 128), blk, 0, stream>>>(p); }

  // ================= STS stream =================
  u16* a_hi  = (u16*)SG;                  // [16384][288] (also aK/aQ slot)
  u16* xin3  = (u16*)SA;                  // [16384][576]
  u16* xc3   = (u16*)SB;                  // [16384][576]
  u16* kp    = (u16*)SC;                  // [16384][576]
  u16* qp    = (u16*)SD;                  // [16384][576]
  float* dlt3 = SC;                       // [16384][576] fp32 (over kp+qp)
  u16* zg3   = (u16*)SE;                  // [16384][576]
  float* xdbl3 = SF;                      // [16384][64]
  u16* y3    = (u16*)SA;                  // [16384][576] (over xin3)
  float* PFt = out2;                      // 64*32*2304 == |out2|

  trans_bf_k<0><<<tgrid, blk, 0, stream>>>(m_high, nullptr, nullptr, nullptr, a_hi, 288);
  { MP p{}; p.A0 = a_hi; p.Wt = w_tin; p.K = 288; p.K1 = 1 << 28; p.Nout = 576;
    p.ldA = 288; p.ldo = 576; p.outB0 = xin3;
    mfma_gemm_k<1><<<dim3(5, 128), blk, 0, stream>>>(p); }
  conv_bf_k<<<dim3(9, 512), blk, 0, stream>>>(xin3, t_conv_w, t_conv_b, xc3, 576);
  trans_bf_k<1><<<tgrid, blk, 0, stream>>>(Kin, t_kln_g, t_kln_b, nullptr, a_hi, 288);
  { MP p{}; p.A0 = a_hi; p.Wt = w_tk; p.K = 288; p.K1 = 1 << 28; p.Nout = 576;
    p.ldA = 288; p.ldo = 576; p.bias = t_k_b; p.outB0 = kp;
    mfma_gemm_k<3><<<dim3(5, 128), blk, 0, stream>>>(p); }
  trans_bf_k<1><<<tgrid, blk, 0, stream>>>(Qin, t_qln_g, t_qln_b, nullptr, a_hi, 288);
  { MP p{}; p.A0 = a_hi; p.Wt = w_tq; p.K = 288; p.K1 = 1 << 28; p.Nout = 576;
    p.ldA = 288; p.ldo = 576; p.bias = t_q_b; p.outB0 = qp;
    mfma_gemm_k<3><<<dim3(5, 128), blk, 0, stream>>>(p); }
  { MP p{}; p.A0 = xc3; p.A1 = kp; p.Wt = w_tdtbc; p.K = 1152; p.K1 = 576;
    p.Nout = 64; p.ldA = 576; p.ldo = 64; p.outF = xdbl3;
    mfma_gemm_k<0><<<dim3(1, 128), blk, 0, stream>>>(p); }
  { MP p{}; p.A0 = xc3; p.A1 = qp; p.Wt = w_tgate; p.K = 1152; p.K1 = 576;
    p.Nout = 576; p.ldA = 576; p.ldo = 576; p.bias = t_gate_b; p.outB0 = zg3;
    mfma_gemm_k<4><<<dim3(5, 128), blk, 0, stream>>>(p); }
  { GemmP p{}; p.A0 = xdbl3; p.lda = 64; p.K = 18; p.W = t_dt_w; p.N = 576;
    p.ebias = t_dt_b; p.out0 = dlt3; p.ldo = 576;
    gemm_f32_k<<<dim3(9, 256), blk, 0, stream>>>(p); }
  scan_tm_k<1><<<dim3(9, 64, 4), blk64, 0, stream>>>(xc3, dlt3, t_Alog, xdbl3, 18, t_D, zg3, PFt, y3, 576, 64, 2304);
  stitch_k<<<dim3(144), blk, 0, stream>>>(PFt, 64, 2304, 36864);
  scan_tm_k<3><<<dim3(9, 64, 4), blk64, 0, stream>>>(xc3, dlt3, t_Alog, xdbl3, 18, t_D, zg3, PFt, y3, 576, 64, 2304);
  { MP p{}; p.A0 = y3; p.Wt = w_tout; p.K = 576; p.K1 = 1 << 28; p.Nout = 288;
    p.ldA = 576; p.res = m_high; p.outF = out2;
    mfma_gemm_k<2><<<dim3(3, 128), blk, 0, stream>>>(p); }
}

// Round 5
// 570.118 us; speedup vs baseline: 5.1540x; 1.0583x over previous
//
#include <hip/hip_runtime.h>
#include <math.h>

// DualStreamBlock: B=4, DIM=96, DIM3=288, H=W=64, L=4096, DSTATE=16
// di=192, di3=576, r=6, r3=18
#define L 4096

typedef unsigned short u16;
typedef float f32x4 __attribute__((ext_vector_type(4)));
typedef short s16x8 __attribute__((ext_vector_type(8)));
typedef __attribute__((address_space(3))) unsigned int lds_u32;
typedef __attribute__((address_space(1))) unsigned int glb_u32;

__device__ __forceinline__ float softplus_f(float x) {
  return fmaxf(x, 0.f) + log1pf(__expf(-fabsf(x)));
}
__device__ __forceinline__ float silu_f(float x) {
  return x / (1.f + __expf(-x));
}
__device__ __forceinline__ float bf2f(u16 v) {
  return __uint_as_float(((unsigned)v) << 16);
}
__device__ __forceinline__ u16 f2bf(float f) {
  unsigned u = __float_as_uint(f);
  u += 0x7FFFu + ((u >> 16) & 1u);
  return (u16)(u >> 16);
}

// ---------------------------------------------------------------------------
// Weight convert: fp32 W[K][N] -> bf16 Wt[Npad][K] (transposed, zero-padded)
// ---------------------------------------------------------------------------
struct WSeg { const float* src; u16* dst; int K, N, Npad; };
struct WAll { WSeg s[9]; };

__global__ __launch_bounds__(256) void wconv_k(WAll wa) {
  const WSeg w = wa.s[blockIdx.z];
  const int nb = blockIdx.x * 32, kb = blockIdx.y * 32;
  if (nb >= w.Npad || kb >= w.K) return;
  __shared__ float t[32][33];
  const int tx = threadIdx.x & 31, ty = threadIdx.x >> 5;
  for (int r = ty; r < 32; r += 8) {
    int k = kb + r, n = nb + tx;
    t[r][tx] = (n < w.N) ? w.src[(size_t)k * w.N + n] : 0.f;
  }
  __syncthreads();
  for (int r = ty; r < 32; r += 8) {
    int n = nb + r;
    w.dst[(size_t)n * w.K + kb + tx] = f2bf(t[tx][r]);
  }
}

// ---------------------------------------------------------------------------
// Tiled transpose prep: chan-major fp32 (B,C,L) -> token-major bf16 [B*L][C]
// DO_LN=1: LayerNorm over C (gamma/beta). DO_LN=0: optional +bias2[b*C+c].
// ---------------------------------------------------------------------------
template<int DO_LN>
__global__ __launch_bounds__(256) void trans_bf_k(
    const float* __restrict__ x, const float* __restrict__ gam,
    const float* __restrict__ bet, const float* __restrict__ bias2,
    u16* __restrict__ out, int C) {
  __shared__ float tile[288][33];
  __shared__ float psum[8][32], psq[8][32];
  __shared__ float mm[32], rr[32];
  const int tid = threadIdx.x;
  const int l0 = blockIdx.x * 32;
  const int b = blockIdx.y;
  const int lane32 = tid & 31, row8 = tid >> 5;
  const float* xb = x + (size_t)b * C * L + l0;

  for (int c = row8; c < C; c += 8)
    tile[c][lane32] = xb[(size_t)c * L + lane32];
  __syncthreads();

  if (DO_LN) {
    float s = 0.f, sq = 0.f;
    for (int c = row8; c < C; c += 8) {
      float v = tile[c][lane32];
      s += v; sq = fmaf(v, v, sq);
    }
    psum[row8][lane32] = s; psq[row8][lane32] = sq;
    __syncthreads();
    if (row8 == 0) {
      float ts = 0.f, tq = 0.f;
      #pragma unroll
      for (int g = 0; g < 8; ++g) { ts += psum[g][lane32]; tq += psq[g][lane32]; }
      float m = ts / C;
      float var = tq / C - m * m;
      mm[lane32] = m;
      rr[lane32] = rsqrtf(var + 1e-5f);
    }
    __syncthreads();
  }

  u16* ob = out + ((size_t)b * L + l0) * C;
  const int total = 32 * C;
  for (int o = tid * 8; o < total; o += 2048) {
    int t = o / C, c = o % C;
    float m = 0.f, rs = 0.f;
    if (DO_LN) { m = mm[t]; rs = rr[t]; }
    union { u16 u[8]; int4 v; } pk;
    #pragma unroll
    for (int j = 0; j < 8; ++j) {
      float v = tile[c + j][t];
      if (DO_LN) v = (v - m) * rs * gam[c + j] + bet[c + j];
      else if (bias2) v += bias2[b * C + c + j];
      pk.u[j] = f2bf(v);
    }
    *(int4*)(ob + o) = pk.v;
  }
}

// ---------------------------------------------------------------------------
// causal depthwise conv k=4 + bias + silu, token-major bf16 in/out
// ---------------------------------------------------------------------------
__global__ __launch_bounds__(256) void conv_bf_k(const u16* __restrict__ x,
    const float* __restrict__ w, const float* __restrict__ bias,
    u16* __restrict__ y, int C) {
  const int c = blockIdx.x * 64 + (threadIdx.x & 63);
  const int chunk = blockIdx.y * 4 + (threadIdx.x >> 6);
  const int T0 = chunk * 8;
  const float w0 = w[c * 4], w1 = w[c * 4 + 1], w2 = w[c * 4 + 2], w3 = w[c * 4 + 3];
  const float bs = bias[c];
  const bool first = (T0 & (L - 1)) == 0;
  float v[11];
  #pragma unroll
  for (int i = 0; i < 11; ++i) {
    if (i < 3 && first) v[i] = 0.f;
    else v[i] = bf2f(x[(size_t)(T0 - 3 + i) * C + c]);
  }
  #pragma unroll
  for (int j = 0; j < 8; ++j) {
    float s = bs + w0 * v[j] + w1 * v[j + 1] + w2 * v[j + 2] + w3 * v[j + 3];
    y[(size_t)(T0 + j) * C + c] = f2bf(silu_f(s));
  }
}

// ---------------------------------------------------------------------------
// MFMA bf16 GEMM: A [M=16384][K] token-major bf16 (optional concat A0|A1),
// Wt [Npad][K] bf16. Tile 128x128, 4 waves (2x2), BK=32.
// 2-phase double-buffered pipeline (stage t+1 before compute t).
// 1-D grid, XCD-bijective swizzle, m-major chunking (A-strip stays on 1 XCD).
// EPI: 0 fp32 row-major; 1 bf16 row-major; 2 chan-major fp32 + residual;
//      3 silu(x+bias) bf16; 4 (x+bias) bf16; 5 split bf16 (out0|out1).
// ---------------------------------------------------------------------------
struct MP {
  const u16 *A0, *A1, *Wt;
  const float *bias, *res;
  float* outF; u16 *outB0, *outB1;
  int K, K1, Nout, ldA, ldo, split, nbx;
};

template<int EPI>
__global__ __launch_bounds__(256) void mfma_gemm_k(MP p) {
  __shared__ u16 As[2][4096];
  __shared__ u16 Bs[2][4096];
  const int tid = threadIdx.x;
  const int lane = tid & 63;
  const int wid = tid >> 6;
  const int wm = wid >> 1, wn = wid & 1;
  // XCD-bijective swizzle (all grids here are multiples of 8; chunk%nbx==0)
  const int nwg = gridDim.x;
  const int wg = blockIdx.x;
  const int newid = (wg & 7) * (nwg >> 3) + (wg >> 3);
  const int n0 = (newid % p.nbx) * 128;
  const int m0 = (newid / p.nbx) * 128;
  const int srow = tid & 127;
  const int skc = tid >> 7;
  const int kgrp = lane >> 4, l16 = lane & 15;

  f32x4 acc[4][4];
  #pragma unroll
  for (int i = 0; i < 4; ++i)
    #pragma unroll
    for (int j = 0; j < 4; ++j)
      acc[i][j] = (f32x4){0.f, 0.f, 0.f, 0.f};

  auto stage = [&](int bi, int k0) {
    const u16* Ab = p.A0;
    int kc = k0;
    if (p.A1 && k0 >= p.K1) { Ab = p.A1; kc = k0 - p.K1; }
    const u16* g0 = Ab + (size_t)(m0 + srow) * p.ldA + kc + skc * 8;
    u16* Ad = &As[bi][0];
    __builtin_amdgcn_global_load_lds((const glb_u32*)g0,
        (lds_u32*)(Ad + wid * 512), 16, 0, 0);
    __builtin_amdgcn_global_load_lds((const glb_u32*)(g0 + 16),
        (lds_u32*)(Ad + 2048 + wid * 512), 16, 0, 0);
    const u16* h0 = p.Wt + (size_t)(n0 + srow) * p.K + k0 + skc * 8;
    u16* Bd = &Bs[bi][0];
    __builtin_amdgcn_global_load_lds((const glb_u32*)h0,
        (lds_u32*)(Bd + wid * 512), 16, 0, 0);
    __builtin_amdgcn_global_load_lds((const glb_u32*)(h0 + 16),
        (lds_u32*)(Bd + 2048 + wid * 512), 16, 0, 0);
  };

  const int nt = p.K >> 5;
  stage(0, 0);
  __syncthreads();
  for (int t = 0; t < nt; ++t) {
    const int cur = t & 1;
    if (t + 1 < nt) stage(cur ^ 1, (t + 1) << 5);
    s16x8 af[4], bfr[4];
    #pragma unroll
    for (int mi = 0; mi < 4; ++mi)
      af[mi] = *(const s16x8*)(&As[cur][0] + kgrp * 1024 + (wm * 64 + mi * 16 + l16) * 8);
    #pragma unroll
    for (int ni = 0; ni < 4; ++ni)
      bfr[ni] = *(const s16x8*)(&Bs[cur][0] + kgrp * 1024 + (wn * 64 + ni * 16 + l16) * 8);
    #pragma unroll
    for (int mi = 0; mi < 4; ++mi)
      #pragma unroll
      for (int ni = 0; ni < 4; ++ni)
        acc[mi][ni] = __builtin_amdgcn_mfma_f32_16x16x32_bf16(af[mi], bfr[ni], acc[mi][ni], 0, 0, 0);
    if (t + 1 < nt) __syncthreads();
  }

  if (EPI == 2) {
    #pragma unroll
    for (int mi = 0; mi < 4; ++mi) {
      int token = m0 + wm * 64 + mi * 16 + (lane >> 4) * 4;
      int b = token >> 12, l = token & (L - 1);
      #pragma unroll
      for (int ni = 0; ni < 4; ++ni) {
        int n = n0 + wn * 64 + ni * 16 + l16;
        if (n < p.Nout) {
          size_t o = ((size_t)b * p.Nout + n) * L + l;
          float4 r = *(const float4*)(p.res + o);
          float4 v = make_float4(acc[mi][ni][0] + r.x, acc[mi][ni][1] + r.y,
                                 acc[mi][ni][2] + r.z, acc[mi][ni][3] + r.w);
          *(float4*)(p.outF + o) = v;
        }
      }
    }
  } else {
    #pragma unroll
    for (int mi = 0; mi < 4; ++mi) {
      #pragma unroll
      for (int j = 0; j < 4; ++j) {
        int token = m0 + wm * 64 + mi * 16 + (lane >> 4) * 4 + j;
        #pragma unroll
        for (int ni = 0; ni < 4; ++ni) {
          int n = n0 + wn * 64 + ni * 16 + l16;
          float v = acc[mi][ni][j];
          if (EPI == 0) {
            if (n < p.Nout) p.outF[(size_t)token * p.ldo + n] = v;
          } else if (EPI == 1) {
            if (n < p.Nout) p.outB0[(size_t)token * p.ldo + n] = f2bf(v);
          } else if (EPI == 3) {
            if (n < p.Nout) p.outB0[(size_t)token * p.ldo + n] = f2bf(silu_f(v + p.bias[n]));
          } else if (EPI == 4) {
            if (n < p.Nout) p.outB0[(size_t)token * p.ldo + n] = f2bf(v + p.bias[n]);
          } else {  // 5: split
            if (n < p.split) p.outB0[(size_t)token * p.split + n] = f2bf(v);
            else p.outB1[(size_t)token * p.split + (n - p.split)] = f2bf(v);
          }
        }
      }
    }
  }
}

// ---------------------------------------------------------------------------
// small fp32 GEMM (dt projection): A row-major [M][lda], W fp32 [K][N],
// EPI: softplus(x + ebias[n]) -> fp32 row-major [M][N]
// ---------------------------------------------------------------------------
struct GemmP {
  const float* A0; const float* W; const float* ebias;
  float* out0;
  int K, N, lda, ldo;
};

__global__ __launch_bounds__(256) void gemm_f32_k(GemmP p) {
  __shared__ __align__(16) float As[16][64];
  __shared__ __align__(16) float Bs[16][64];
  const int tid = threadIdx.x;
  const int kidx = tid >> 4;
  const int li4 = (tid & 15) << 2;
  const int r0 = (tid & 15) << 2;
  const int c0 = (tid >> 4) << 2;
  const int n0 = blockIdx.x * 64;
  const int m0 = blockIdx.y * 64;
  float acc[4][4] = {};

  for (int k0 = 0; k0 < p.K; k0 += 16) {
    __syncthreads();
    {
      const int row = tid >> 2;
      const int kk4 = (tid & 3) << 2;
      const float* src = p.A0 + (size_t)(m0 + row) * p.lda;
      #pragma unroll
      for (int j = 0; j < 4; ++j) {
        int k = k0 + kk4 + j;
        As[kk4 + j][row] = (k < p.K) ? src[k] : 0.f;
      }
    }
    {
      int k = k0 + kidx;
      #pragma unroll
      for (int j = 0; j < 4; ++j) {
        int n = n0 + li4 + j;
        Bs[kidx][li4 + j] = (k < p.K && n < p.N) ? p.W[(size_t)k * p.N + n] : 0.f;
      }
    }
    __syncthreads();
    #pragma unroll
    for (int kk = 0; kk < 16; ++kk) {
      float4 a = *(const float4*)&As[kk][r0];
      float4 bq = *(const float4*)&Bs[kk][c0];
      float av[4] = {a.x, a.y, a.z, a.w};
      float bv[4] = {bq.x, bq.y, bq.z, bq.w};
      #pragma unroll
      for (int i = 0; i < 4; ++i)
        #pragma unroll
        for (int j = 0; j < 4; ++j)
          acc[i][j] = fmaf(av[i], bv[j], acc[i][j]);
    }
  }
  float eb[4] = {p.ebias[n0 + c0], p.ebias[n0 + c0 + 1], p.ebias[n0 + c0 + 2], p.ebias[n0 + c0 + 3]};
  #pragma unroll
  for (int i = 0; i < 4; ++i) {
    float4 v;
    v.x = softplus_f(acc[i][0] + eb[0]);
    v.y = softplus_f(acc[i][1] + eb[1]);
    v.z = softplus_f(acc[i][2] + eb[2]);
    v.w = softplus_f(acc[i][3] + eb[3]);
    *(float4*)&p.out0[(size_t)(m0 + r0 + i) * p.ldo + n0 + c0] = v;
  }
}

// ---------------------------------------------------------------------------
// Chunked selective scan, token-major. u,z,y bf16 [B*L][Dch]; dlt fp32;
// xdbl fp32 [B*L][64], B at roff.., C at roff+16..
// PF layout [c][slot 0..31][NCH] fp32: slots 0..15 = P, 16..31 = F/Hin.
// ---------------------------------------------------------------------------
template<int PASS>
__global__ __launch_bounds__(64) void scan_tm_k(
    const u16* __restrict__ u, const float* __restrict__ dlt,
    const float* __restrict__ Alog, const float* __restrict__ xdbl, int roff,
    const float* __restrict__ Dp, const u16* __restrict__ zT,
    float* __restrict__ PF, u16* __restrict__ yT,
    int Dch, int CLen, int NCH)
{
  const int d = blockIdx.x * 64 + threadIdx.x;
  const int c = blockIdx.y;
  const int b = blockIdx.z;
  const int ch = b * Dch + d;
  const size_t tok0 = (size_t)b * L + (size_t)c * CLen;
  float An[16], h[16], P[16];
  #pragma unroll
  for (int n = 0; n < 16; ++n) {
    An[n] = -__expf(Alog[d * 16 + n]);
    P[n] = 1.f; h[n] = 0.f;
  }
  if (PASS == 3) {
    #pragma unroll
    for (int n2 = 0; n2 < 16; ++n2)
      h[n2] = PF[((size_t)c * 32 + 16 + n2) * NCH + ch];
  }
  const float Dd = Dp[d];
  const u16* up = u + tok0 * Dch + d;
  const float* dp = dlt + tok0 * Dch + d;
  const u16* zp = zT + tok0 * Dch + d;
  u16* yr = yT + tok0 * Dch + d;
  const float* xr = xdbl + tok0 * 64 + roff;
  for (int t = 0; t < CLen; ++t) {
    const size_t od = (size_t)t * Dch;
    float dl = dp[od];
    float uu = bf2f(up[od]);
    float w = dl * uu;
    const float2* bp = (const float2*)(xr + (size_t)t * 64);
    float y = 0.f;
    #pragma unroll
    for (int q = 0; q < 8; ++q) {
      float2 bv = bp[q];
      float a0 = __expf(dl * An[2 * q]);
      float a1 = __expf(dl * An[2 * q + 1]);
      h[2 * q]     = fmaf(a0, h[2 * q],     w * bv.x);
      h[2 * q + 1] = fmaf(a1, h[2 * q + 1], w * bv.y);
      if (PASS == 1) {
        P[2 * q] *= a0; P[2 * q + 1] *= a1;
      } else {
        float2 cv = bp[q + 8];
        y = fmaf(h[2 * q], cv.x, y);
        y = fmaf(h[2 * q + 1], cv.y, y);
      }
    }
    if (PASS == 3) {
      float zv = bf2f(zp[od]);
      yr[od] = f2bf((y + Dd * uu) * silu_f(zv));
    }
  }
  if (PASS == 1) {
    #pragma unroll
    for (int n2 = 0; n2 < 16; ++n2) {
      PF[((size_t)c * 32 + n2) * NCH + ch] = P[n2];
      PF[((size_t)c * 32 + 16 + n2) * NCH + ch] = h[n2];
    }
  }
}

// Stitch: per (ch, state n) sequential over chunks; rewrites F slot with Hin.
__global__ __launch_bounds__(256) void stitch_k(float* __restrict__ PF,
    int NC, int NCH, int total) {
  int idx = blockIdx.x * 256 + threadIdx.x;
  if (idx >= total) return;
  int ch = idx % NCH, n = idx / NCH;
  float hin = 0.f;
  for (int c = 0; c < NC; ++c) {
    float* Ps = PF + ((size_t)c * 32 + n) * NCH + ch;
    float* Fs = PF + ((size_t)c * 32 + 16 + n) * NCH + ch;
    float Pv = *Ps, Fv = *Fs;
    *Fs = hin;
    hin = fmaf(Pv, hin, Fv);
  }
}

// ---------------------------------------------------------------------------
extern "C" void kernel_launch(void* const* d_in, const int* in_sizes, int n_in,
                              void* d_out, int out_size, void* d_ws, size_t ws_size,
                              hipStream_t stream) {
  const float* m_ll    = (const float*)d_in[0];
  const float* m_high  = (const float*)d_in[1];
  const float* zanc    = (const float*)d_in[2];
  const float* Kin     = (const float*)d_in[3];
  const float* Qin     = (const float*)d_in[4];
  const float* s_in_w  = (const float*)d_in[5];
  const float* s_conv_w= (const float*)d_in[6];
  const float* s_conv_b= (const float*)d_in[7];
  const float* s_x_w   = (const float*)d_in[8];
  const float* s_dt_w  = (const float*)d_in[9];
  const float* s_dt_b  = (const float*)d_in[10];
  const float* s_Alog  = (const float*)d_in[11];
  const float* s_D     = (const float*)d_in[12];
  const float* s_out_w = (const float*)d_in[13];
  const float* t_in_w  = (const float*)d_in[14];
  const float* t_conv_w= (const float*)d_in[15];
  const float* t_conv_b= (const float*)d_in[16];
  const float* t_kln_g = (const float*)d_in[17];
  const float* t_kln_b = (const float*)d_in[18];
  const float* t_k_w   = (const float*)d_in[19];
  const float* t_k_b   = (const float*)d_in[20];
  const float* t_qln_g = (const float*)d_in[21];
  const float* t_qln_b = (const float*)d_in[22];
  const float* t_q_w   = (const float*)d_in[23];
  const float* t_q_b   = (const float*)d_in[24];
  const float* t_dtbc_w= (const float*)d_in[25];
  const float* t_dt_w  = (const float*)d_in[26];
  const float* t_dt_b  = (const float*)d_in[27];
  const float* t_gate_w= (const float*)d_in[28];
  const float* t_gate_b= (const float*)d_in[29];
  const float* t_Alog  = (const float*)d_in[30];
  const float* t_D     = (const float*)d_in[31];
  const float* t_out_w = (const float*)d_in[32];

  float* out1 = (float*)d_out;               // (4, 96, 4096)  = 1,572,864 f
  float* out2 = out1 + (size_t)4 * 96 * L;   // (4, 288, 4096) = 4,718,592 f
  float* ws = (float*)d_ws;

  // Weight region (bf16)
  u16* w_sin   = (u16*)(ws + 0);        // [384][96]
  u16* w_sx    = (u16*)(ws + 18432);    // [128][192]
  u16* w_sout  = (u16*)(ws + 30720);    // [128][192]
  u16* w_tin   = (u16*)(ws + 43008);    // [640][288]
  u16* w_tk    = (u16*)(ws + 135168);   // [640][288]
  u16* w_tq    = (u16*)(ws + 227328);   // [640][288]
  u16* w_tdtbc = (u16*)(ws + 319488);   // [128][1152]
  u16* w_tgate = (u16*)(ws + 393216);   // [640][1152]
  u16* w_tout  = (u16*)(ws + 761856);   // [384][576]
  // Big slots (float offsets)
  float* SA = ws + 872448;    // 4,718,592 f
  float* SB = ws + 5591040;   // 4,718,592 f
  float* SC = ws + 10309632;  // 4,718,592 f
  float* SD = ws + 15028224;  // 4,718,592 f
  float* SE = ws + 19746816;  // 4,718,592 f
  float* SF = ws + 24465408;  // 1,048,576 f
  float* SG = ws + 25513984;  // 2,359,296 f

  dim3 blk(256);
  dim3 blk64(64);
  dim3 tgrid(128, 4);

  // ---- weight conversion (9 segments) ----
  {
    WAll wa;
    wa.s[0] = {s_in_w,   w_sin,    96, 384, 384};
    wa.s[1] = {s_x_w,    w_sx,    192,  38, 128};
    wa.s[2] = {s_out_w,  w_sout,  192,  96, 128};
    wa.s[3] = {t_in_w,   w_tin,   288, 576, 640};
    wa.s[4] = {t_k_w,    w_tk,    288, 576, 640};
    wa.s[5] = {t_q_w,    w_tq,    288, 576, 640};
    wa.s[6] = {t_dtbc_w, w_tdtbc, 1152, 50, 128};
    wa.s[7] = {t_gate_w, w_tgate, 1152, 576, 640};
    wa.s[8] = {t_out_w,  w_tout,  576, 288, 384};
    wconv_k<<<dim3(20, 36, 9), blk, 0, stream>>>(wa);
  }

  // ================= SSS stream =================
  u16* a_ll  = (u16*)SG;                  // [16384][96]
  u16* x_in  = (u16*)SA;                  // [16384][192]
  u16* zTs   = (u16*)(SA + 1572864);      // [16384][192]
  u16* xc    = (u16*)SB;                  // [16384][192]
  float* xdbl = SF;                       // [16384][64]
  float* dlt  = SC;                       // [16384][192] fp32
  u16* y_bf  = (u16*)SD;                  // [16384][192]
  float* PFs  = SE;                       // 128*32*768

  trans_bf_k<0><<<tgrid, blk, 0, stream>>>(m_ll, nullptr, nullptr, zanc, a_ll, 96);
  { MP p{}; p.A0 = a_ll; p.Wt = w_sin; p.K = 96; p.K1 = 1 << 28; p.Nout = 384;
    p.ldA = 96; p.split = 192; p.outB0 = x_in; p.outB1 = zTs; p.nbx = 3;
    mfma_gemm_k<5><<<dim3(3 * 128), blk, 0, stream>>>(p); }
  conv_bf_k<<<dim3(3, 512), blk, 0, stream>>>(x_in, s_conv_w, s_conv_b, xc, 192);
  { MP p{}; p.A0 = xc; p.Wt = w_sx; p.K = 192; p.K1 = 1 << 28; p.Nout = 64;
    p.ldA = 192; p.ldo = 64; p.outF = xdbl; p.nbx = 1;
    mfma_gemm_k<0><<<dim3(128), blk, 0, stream>>>(p); }
  { GemmP p{}; p.A0 = xdbl; p.lda = 64; p.K = 6; p.W = s_dt_w; p.N = 192;
    p.ebias = s_dt_b; p.out0 = dlt; p.ldo = 192;
    gemm_f32_k<<<dim3(3, 256), blk, 0, stream>>>(p); }
  scan_tm_k<1><<<dim3(3, 128, 4), blk64, 0, stream>>>(xc, dlt, s_Alog, xdbl, 6, s_D, zTs, PFs, y_bf, 192, 32, 768);
  stitch_k<<<dim3(48), blk, 0, stream>>>(PFs, 128, 768, 12288);
  scan_tm_k<3><<<dim3(3, 128, 4), blk64, 0, stream>>>(xc, dlt, s_Alog, xdbl, 6, s_D, zTs, PFs, y_bf, 192, 32, 768);
  { MP p{}; p.A0 = y_bf; p.Wt = w_sout; p.K = 192; p.K1 = 1 << 28; p.Nout = 96;
    p.ldA = 192; p.res = m_ll; p.outF = out1; p.nbx = 1;
    mfma_gemm_k<2><<<dim3(128), blk, 0, stream>>>(p); }

  // ================= STS stream =================
  u16* a_hi  = (u16*)SG;                  // [16384][288] (also aK/aQ slot)
  u16* xin3  = (u16*)SA;                  // [16384][576]
  u16* xc3   = (u16*)SB;                  // [16384][576]
  u16* kp    = (u16*)SC;                  // [16384][576]
  u16* qp    = (u16*)SD;                  // [16384][576]
  float* dlt3 = SC;                       // [16384][576] fp32 (over kp+qp)
  u16* zg3   = (u16*)SE;                  // [16384][576]
  float* xdbl3 = SF;                      // [16384][64]
  u16* y3    = (u16*)SA;                  // [16384][576] (over xin3)
  float* PFt = out2;                      // 64*32*2304 == |out2|

  trans_bf_k<0><<<tgrid, blk, 0, stream>>>(m_high, nullptr, nullptr, nullptr, a_hi, 288);
  { MP p{}; p.A0 = a_hi; p.Wt = w_tin; p.K = 288; p.K1 = 1 << 28; p.Nout = 576;
    p.ldA = 288; p.ldo = 576; p.outB0 = xin3; p.nbx = 5;
    mfma_gemm_k<1><<<dim3(5 * 128), blk, 0, stream>>>(p); }
  conv_bf_k<<<dim3(9, 512), blk, 0, stream>>>(xin3, t_conv_w, t_conv_b, xc3, 576);
  trans_bf_k<1><<<tgrid, blk, 0, stream>>>(Kin, t_kln_g, t_kln_b, nullptr, a_hi, 288);
  { MP p{}; p.A0 = a_hi; p.Wt = w_tk; p.K = 288; p.K1 = 1 << 28; p.Nout = 576;
    p.ldA = 288; p.ldo = 576; p.bias = t_k_b; p.outB0 = kp; p.nbx = 5;
    mfma_gemm_k<3><<<dim3(5 * 128), blk, 0, stream>>>(p); }
  trans_bf_k<1><<<tgrid, blk, 0, stream>>>(Qin, t_qln_g, t_qln_b, nullptr, a_hi, 288);
  { MP p{}; p.A0 = a_hi; p.Wt = w_tq; p.K = 288; p.K1 = 1 << 28; p.Nout = 576;
    p.ldA = 288; p.ldo = 576; p.bias = t_q_b; p.outB0 = qp; p.nbx = 5;
    mfma_gemm_k<3><<<dim3(5 * 128), blk, 0, stream>>>(p); }
  { MP p{}; p.A0 = xc3; p.A1 = kp; p.Wt = w_tdtbc; p.K = 1152; p.K1 = 576;
    p.Nout = 64; p.ldA = 576; p.ldo = 64; p.outF = xdbl3; p.nbx = 1;
    mfma_gemm_k<0><<<dim3(128), blk, 0, stream>>>(p); }
  { MP p{}; p.A0 = xc3; p.A1 = qp; p.Wt = w_tgate; p.K = 1152; p.K1 = 576;
    p.Nout = 576; p.ldA = 576; p.ldo = 576; p.bias = t_gate_b; p.outB0 = zg3; p.nbx = 5;
    mfma_gemm_k<4><<<dim3(5 * 128), blk, 0, stream>>>(p); }
  { GemmP p{}; p.A0 = xdbl3; p.lda = 64; p.K = 18; p.W = t_dt_w; p.N = 576;
    p.ebias = t_dt_b; p.out0 = dlt3; p.ldo = 576;
    gemm_f32_k<<<dim3(9, 256), blk, 0, stream>>>(p); }
  scan_tm_k<1><<<dim3(9, 64, 4), blk64, 0, stream>>>(xc3, dlt3, t_Alog, xdbl3, 18, t_D, zg3, PFt, y3, 576, 64, 2304);
  stitch_k<<<dim3(144), blk, 0, stream>>>(PFt, 64, 2304, 36864);
  scan_tm_k<3><<<dim3(9, 64, 4), blk64, 0, stream>>>(xc3, dlt3, t_Alog, xdbl3, 18, t_D, zg3, PFt, y3, 576, 64, 2304);
  { MP p{}; p.A0 = y3; p.Wt = w_tout; p.K = 576; p.K1 = 1 << 28; p.Nout = 288;
    p.ldA = 576; p.res = m_high; p.outF = out2; p.nbx = 3;
    mfma_gemm_k<2><<<dim3(3 * 128), blk, 0, stream>>>(p); }
}